// Round 8
// baseline (174.187 us; speedup 1.0000x reference)
//
#include <hip/hip_runtime.h>
#include <math.h>

#define BN 8192
#define CN 1000
#define DN 128
#define INVT (1.0f/0.3f)
#define EXP2C 4.80898346962988f   // (1/0.3) * log2(e)
#define NEGBIG (-1e30f)           // finite sentinel: avoids exp(-inf - -inf)=NaN

typedef __bf16 bf16x8 __attribute__((ext_vector_type(8)));
typedef float  f32x4  __attribute__((ext_vector_type(4)));

// ws layout in floats
#define F_FEATN  0          // 8192*128
#define F_MEANSN 1048576    // 1000*128
#define F_XX     1176576    // 8192
#define F_YY     1184768    // 1000
#define F_DIAG   1185768    // 8192
#define F_FEATB  1193960    // 8192*128 bf16
#define F_MEANSB 1718248    // 1024*128 bf16 (raw, zero-padded)
#define F_CEROW  1783784    // 8192
#define F_MROW   1791976    // 8192
#define F_POSR   1800168    // 8192
#define F_PM     1808360    // 4*8192 CE partial max
#define F_PL     1841128    // 4*8192 CE partial sum
#define F_BOT    1873896    // 8192  -- zeroed region start
#define F_CNT    1882088    // 1000 ints
#define F_CSUM   1883088    // 1000*128 (zeroed)

// mega-kernel block ranges (LDS-free, 4 waves/SIMD)
#define NB_SCL  544   // 2176 waves: 32 i-rows x <=16 triangular 32-col j-tiles
#define NB_NSD  256   // 1024 waves: 32 rows x 256 cols
#define NB_CSUM 256

// -------- feat: L2-normalize + bf16 copy + diag + label histogram --------
__global__ void norm_feat(const float* __restrict__ src, float* __restrict__ dst,
                          float* __restrict__ sq, __bf16* __restrict__ dstb,
                          float* __restrict__ diag, const int* __restrict__ labels,
                          int* __restrict__ counts) {
    int row = blockIdx.x * 4 + (threadIdx.x >> 6);
    int lane = threadIdx.x & 63;
    float f0 = src[row * DN + lane];
    float f1 = src[row * DN + 64 + lane];
    float ss = f0 * f0 + f1 * f1;
    #pragma unroll
    for (int o = 32; o > 0; o >>= 1) ss += __shfl_xor(ss, o);
    float inv = 1.0f / fmaxf(sqrtf(ss), 1e-12f);
    float n0 = f0 * inv, n1 = f1 * inv;
    dst[row * DN + lane] = n0;
    dst[row * DN + 64 + lane] = n1;
    __bf16 b0 = (__bf16)n0, b1 = (__bf16)n1;
    dstb[row * DN + lane] = b0;
    dstb[row * DN + 64 + lane] = b1;
    float fb0 = (float)b0, fb1 = (float)b1;
    float sb = fb0 * fb0 + fb1 * fb1;
    #pragma unroll
    for (int o = 32; o > 0; o >>= 1) sb += __shfl_xor(sb, o);
    if (lane == 0) {
        diag[row] = sb;
        sq[row] = ss * inv * inv;
        atomicAdd(&counts[labels[row]], 1);
    }
}

// -------- means: normalize (fp32) + yy + raw-bf16 copy padded to 1024 rows --------
__global__ void norm_means(const float* __restrict__ src, float* __restrict__ dst,
                           float* __restrict__ sq, __bf16* __restrict__ dstb) {
    int row = blockIdx.x * 4 + (threadIdx.x >> 6);   // 0..1023
    int lane = threadIdx.x & 63;
    float f0 = (row < CN) ? src[row * DN + lane] : 0.f;
    float f1 = (row < CN) ? src[row * DN + 64 + lane] : 0.f;
    dstb[row * DN + lane] = (__bf16)f0;
    dstb[row * DN + 64 + lane] = (__bf16)f1;
    if (row >= CN) return;
    float ss = f0 * f0 + f1 * f1;
    #pragma unroll
    for (int o = 32; o > 0; o >>= 1) ss += __shfl_xor(ss, o);
    float inv = 1.0f / fmaxf(sqrtf(ss), 1e-12f);
    dst[row * DN + lane] = f0 * inv;
    dst[row * DN + 64 + lane] = f1 * inv;
    if (lane == 0) sq[row] = ss;
}

// load 2 B-fragments (one k-chunk of a 32-col tile) straight from global/L2
__device__ __forceinline__ void loadB2(bf16x8* b, const uint4* __restrict__ src,
                                       int j0, int kk, int l15, int q) {
    #pragma unroll
    for (int jj = 0; jj < 2; jj++)
        b[jj] = *(const bf16x8*)&src[(size_t)(j0 + jj * 16 + l15) * 16 + kk * 4 + q];
}

// -------- mega kernel (LDS-free, 4 waves/SIMD):
//   [0,544) scl-tri | [544,800) nsd | [800,1056) csum --------
__global__ __launch_bounds__(256, 4) void mega_kernel(
        const __bf16* __restrict__ featb, const __bf16* __restrict__ meansb,
        const float* __restrict__ featn, const int* __restrict__ labels,
        const float* __restrict__ xx, const float* __restrict__ yy,
        float* __restrict__ out, float* __restrict__ pm, float* __restrict__ pl,
        float* __restrict__ bottom, float* __restrict__ csum) {
    int bx = blockIdx.x;
    int tid = threadIdx.x;
    int lane = tid & 63, w = tid >> 6;
    int q = lane >> 4, l15 = lane & 15;

    if (bx < NB_SCL) {
        // ---- SCL: wave = 32 i-rows x <=16 triangular 32-col j-tiles ----
        int cid = bx * 4 + w;                 // 0..2175
        int g = 0;
        while (cid >= 16 * (16 - g)) { cid -= 16 * (16 - g); ++g; }
        int per = 16 - g, io = 0;
        while (cid >= per) { cid -= per; ++io; }
        int I = 16 * g + io;                  // 32-row i-block 0..255
        int J0 = I + 16 * cid;                // first 32-col j-tile
        int jend = min(J0 + 16, 256);
        int i0 = I * 32;
        const uint4* fv = (const uint4*)featb;

        bf16x8 af[2][4];
        #pragma unroll
        for (int ii = 0; ii < 2; ii++)
            #pragma unroll
            for (int kk = 0; kk < 4; kk++)
                af[ii][kk] = *(const bf16x8*)&fv[(size_t)(i0 + ii * 16 + l15) * 16 + kk * 4 + q];
        float bs[2][4] = {};

        bf16x8 b[2][2];
        loadB2(b[0], fv, J0 * 32, 0, l15, q);
        for (int J = J0; J < jend; J++) {
            int j0 = J * 32;
            int jn = (J + 1 < jend) ? (J + 1) * 32 : j0;
            f32x4 acc[2][2];
            #pragma unroll
            for (int ii = 0; ii < 2; ii++)
                #pragma unroll
                for (int jj = 0; jj < 2; jj++) acc[ii][jj] = (f32x4){0.f, 0.f, 0.f, 0.f};
            #pragma unroll
            for (int kk = 0; kk < 4; kk++) {
                if (kk < 3) loadB2(b[(kk + 1) & 1], fv, j0, kk + 1, l15, q);
                else        loadB2(b[0], fv, jn, 0, l15, q);   // next visit's kk=0
                #pragma unroll
                for (int ii = 0; ii < 2; ii++)
                    #pragma unroll
                    for (int jj = 0; jj < 2; jj++)
                        acc[ii][jj] = __builtin_amdgcn_mfma_f32_16x16x32_bf16(
                            af[ii][kk], b[kk & 1][jj], acc[ii][jj], 0, 0, 0);
            }
            float cp[2] = {0.f, 0.f};
            #pragma unroll
            for (int ii = 0; ii < 2; ii++)
                #pragma unroll
                for (int jj = 0; jj < 2; jj++)
                    #pragma unroll
                    for (int r4 = 0; r4 < 4; r4++) {
                        float e = exp2f(acc[ii][jj][r4] * EXP2C);
                        bs[ii][r4] += e;
                        cp[jj] += e;
                    }
            if (J != I) {      // mirror: column sums -> bottom[j] (skip diagonal tile)
                #pragma unroll
                for (int jj = 0; jj < 2; jj++) {
                    float c = cp[jj];
                    c += __shfl_xor(c, 16);
                    c += __shfl_xor(c, 32);
                    if (lane < 16)
                        atomicAdd(&bottom[j0 + jj * 16 + l15], c);
                }
            }
        }
        #pragma unroll
        for (int ii = 0; ii < 2; ii++)
            #pragma unroll
            for (int r4 = 0; r4 < 4; r4++) {
                float bsum = bs[ii][r4];
                #pragma unroll
                for (int o = 8; o > 0; o >>= 1) bsum += __shfl_xor(bsum, o);
                if (l15 == 0) atomicAdd(&bottom[i0 + ii * 16 + q * 4 + r4], bsum);
            }

    } else if (bx < NB_SCL + NB_NSD) {
        // ---- NSD: wave = 32 rows x 256 cols (8 steps of 32), local online-softmax ----
        int wid = (bx - NB_SCL) * 4 + w;      // 0..1023
        int ib = wid >> 2, qtr = wid & 3;
        int i0 = ib * 32;
        const uint4* fv = (const uint4*)featb;
        const uint4* mv = (const uint4*)meansb;
        bf16x8 af[2][4];
        #pragma unroll
        for (int ii = 0; ii < 2; ii++)
            #pragma unroll
            for (int kk = 0; kk < 4; kk++)
                af[ii][kk] = *(const bf16x8*)&fv[(size_t)(i0 + ii * 16 + l15) * 16 + kk * 4 + q];
        float mrow[2][4], srow[2][4], xa[2][4];
        int la[2][4];
        #pragma unroll
        for (int ii = 0; ii < 2; ii++) {
            int rbase = i0 + ii * 16 + q * 4;
            int4 lv = ((const int4*)labels)[rbase >> 2];
            float4 xv = ((const float4*)xx)[rbase >> 2];
            la[ii][0] = lv.x; la[ii][1] = lv.y; la[ii][2] = lv.z; la[ii][3] = lv.w;
            xa[ii][0] = xv.x; xa[ii][1] = xv.y; xa[ii][2] = xv.z; xa[ii][3] = xv.w;
            #pragma unroll
            for (int r4 = 0; r4 < 4; r4++) { mrow[ii][r4] = NEGBIG; srow[ii][r4] = 0.f; }
        }
        bf16x8 b[2][2];
        loadB2(b[0], mv, qtr * 256, 0, l15, q);
        for (int s = 0; s < 8; s++) {
            int j0 = qtr * 256 + s * 32;
            int jn = (s < 7) ? j0 + 32 : j0;
            f32x4 acc[2][2];
            #pragma unroll
            for (int ii = 0; ii < 2; ii++)
                #pragma unroll
                for (int jj = 0; jj < 2; jj++) acc[ii][jj] = (f32x4){0.f, 0.f, 0.f, 0.f};
            #pragma unroll
            for (int kk = 0; kk < 4; kk++) {
                if (kk < 3) loadB2(b[(kk + 1) & 1], mv, j0, kk + 1, l15, q);
                else        loadB2(b[0], mv, jn, 0, l15, q);
                #pragma unroll
                for (int ii = 0; ii < 2; ii++)
                    #pragma unroll
                    for (int jj = 0; jj < 2; jj++)
                        acc[ii][jj] = __builtin_amdgcn_mfma_f32_16x16x32_bf16(
                            af[ii][kk], b[kk & 1][jj], acc[ii][jj], 0, 0, 0);
            }
            int c0 = j0 + l15, c1 = j0 + 16 + l15;
            float yv0 = (c0 < CN) ? yy[c0] : 0.f;
            float yv1 = (c1 < CN) ? yy[c1] : 0.f;
            #pragma unroll
            for (int ii = 0; ii < 2; ii++)
                #pragma unroll
                for (int r4 = 0; r4 < 4; r4++) {
                    int ig = i0 + ii * 16 + q * 4 + r4;
                    float v0 = -0.5f * (xa[ii][r4] - 2.f * acc[ii][0][r4] + yv0);
                    float v1 = -0.5f * (xa[ii][r4] - 2.f * acc[ii][1][r4] + yv1);
                    if (c0 < CN) out[(size_t)ig * CN + c0] = v0;
                    if (c1 < CN) out[(size_t)ig * CN + c1] = v1;
                    float l0 = (c0 == la[ii][r4]) ? 1.5f * v0 : v0;
                    float l1 = (c1 == la[ii][r4]) ? 1.5f * v1 : v1;
                    if (c0 >= CN) l0 = NEGBIG;   // finite sentinel: tm stays finite,
                    if (c1 >= CN) l1 = NEGBIG;   // junk at level -1e30 underflows to 0
                    float tm = fmaxf(l0, l1);
                    float ts = __expf(l0 - tm) + __expf(l1 - tm);
                    float M = fmaxf(mrow[ii][r4], tm);
                    srow[ii][r4] = srow[ii][r4] * __expf(mrow[ii][r4] - M) + ts * __expf(tm - M);
                    mrow[ii][r4] = M;
                }
        }
        #pragma unroll
        for (int ii = 0; ii < 2; ii++)
            #pragma unroll
            for (int r4 = 0; r4 < 4; r4++) {
                float m = mrow[ii][r4], s2 = srow[ii][r4];
                #pragma unroll
                for (int o = 8; o > 0; o >>= 1) {
                    float mo = __shfl_xor(m, o), so = __shfl_xor(s2, o);
                    float M = fmaxf(m, mo);
                    s2 = s2 * __expf(m - M) + so * __expf(mo - M);
                    m = M;
                }
                if (l15 == 0) {
                    int ig = i0 + ii * 16 + q * 4 + r4;
                    pm[qtr * BN + ig] = m;
                    pl[qtr * BN + ig] = s2;
                }
            }

    } else {
        // ---- csum: class-sum vectors via atomics ----
        int b2 = bx - NB_SCL - NB_NSD;
        for (int idx = b2 * 256 + tid; idx < BN * DN; idx += NB_CSUM * 256) {
            int row = idx >> 7, d = idx & 127;
            atomicAdd(&csum[labels[row] * DN + d], featn[idx]);
        }
    }
}

// -------- fused: margin + pos dots + CE final (4 partials + out-gather) --------
__global__ void cemp_kernel(const float* __restrict__ featn, const float* __restrict__ meansn,
        const float* __restrict__ csum, const int* __restrict__ labels,
        const float* __restrict__ pm, const float* __restrict__ pl,
        const float* __restrict__ out, float* __restrict__ m_row,
        float* __restrict__ pos_row, float* __restrict__ ce_row) {
    int row = blockIdx.x * 4 + (threadIdx.x >> 6);
    int lane = threadIdx.x & 63;
    int lab = labels[row];
    float f0 = featn[row * DN + lane],  f1 = featn[row * DN + 64 + lane];
    float m0 = meansn[lab * DN + lane], m1 = meansn[lab * DN + 64 + lane];
    float c0 = csum[lab * DN + lane],   c1 = csum[lab * DN + 64 + lane];
    float d0 = f0 - m0, d1 = f1 - m1;
    float ss = d0 * d0 + d1 * d1;
    float pp = f0 * c0 + f1 * c1;
    #pragma unroll
    for (int o = 32; o > 0; o >>= 1) {
        ss += __shfl_xor(ss, o);
        pp += __shfl_xor(pp, o);
    }
    if (lane == 0) {
        m_row[row] = ss;
        pos_row[row] = pp;
        float M = NEGBIG;
        #pragma unroll
        for (int k = 0; k < 4; k++) M = fmaxf(M, pm[k * BN + row]);
        float S = 0.f;
        #pragma unroll
        for (int k = 0; k < 4; k++) S += pl[k * BN + row] * __expf(pm[k * BN + row] - M);
        ce_row[row] = (M + logf(S)) - 1.5f * out[(size_t)row * CN + lab];
    }
}

__global__ void final_kernel(const float* __restrict__ bottom, const float* __restrict__ pos_row,
        const int* __restrict__ labels, const int* __restrict__ counts,
        const float* __restrict__ ce_row, const float* __restrict__ m_row,
        const float* __restrict__ diag, const float* __restrict__ xx,
        float* __restrict__ loss_out) {
    int tid = threadIdx.x;
    float sp = 0.f, nv = 0.f, ce = 0.f, mg = 0.f;
    for (int i = tid; i < BN; i += 256) {
        ce += ce_row[i];
        mg += m_row[i];
        float bot = bottom[i] - __expf(diag[i] * INVT);   // exclude j==i (bf16 diag)
        float pv = (pos_row[i] - xx[i]) * INVT;           // exclude j==i (fp32), apply 1/T
        int c = counts[labels[i]] - 1;
        if (c > 0) {
            sp += pv / (float)c - logf(bot);
            nv += 1.f;
        }
    }
    #pragma unroll
    for (int o = 32; o > 0; o >>= 1) {
        sp += __shfl_xor(sp, o);
        nv += __shfl_xor(nv, o);
        ce += __shfl_xor(ce, o);
        mg += __shfl_xor(mg, o);
    }
    __shared__ float r1[4], r2[4], r3[4], r4[4];
    int w = tid >> 6, lane = tid & 63;
    if (lane == 0) { r1[w] = sp; r2[w] = nv; r3[w] = ce; r4[w] = mg; }
    __syncthreads();
    if (tid == 0) {
        float SP = r1[0] + r1[1] + r1[2] + r1[3];
        float NV = r2[0] + r2[1] + r2[2] + r2[3];
        float CE = r3[0] + r3[1] + r3[2] + r3[3];
        float MG = r4[0] + r4[1] + r4[2] + r4[3];
        float scl = -SP / fmaxf(NV, 1.f);
        loss_out[0] = 0.9f * (CE / (float)BN) + 0.1f * scl + 0.5f * (MG / (2.f * (float)BN));
    }
}

extern "C" void kernel_launch(void* const* d_in, const int* in_sizes, int n_in,
                              void* d_out, int out_size, void* d_ws, size_t ws_size,
                              hipStream_t stream) {
    const float* feat   = (const float*)d_in[0];
    const int*   labels = (const int*)d_in[1];
    const float* means  = (const float*)d_in[2];
    float* out = (float*)d_out;
    float* ws  = (float*)d_ws;

    float*  featn  = ws + F_FEATN;
    float*  meansn = ws + F_MEANSN;
    float*  xx     = ws + F_XX;
    float*  yy     = ws + F_YY;
    float*  diag   = ws + F_DIAG;
    __bf16* featb  = (__bf16*)(ws + F_FEATB);
    __bf16* meansb = (__bf16*)(ws + F_MEANSB);
    float*  ce_row = ws + F_CEROW;
    float*  m_row  = ws + F_MROW;
    float*  posr   = ws + F_POSR;
    float*  pm     = ws + F_PM;
    float*  pl     = ws + F_PL;
    float*  bottom = ws + F_BOT;
    int*    counts = (int*)(ws + F_CNT);
    float*  csum   = ws + F_CSUM;

    // zero bottom + counts + csum (contiguous)
    hipMemsetAsync(ws + F_BOT, 0, (size_t)(8192 + 1000 + 128000) * sizeof(float), stream);

    norm_feat<<<2048, 256, 0, stream>>>(feat, featn, xx, featb, diag, labels, counts);
    norm_means<<<256, 256, 0, stream>>>(means, meansn, yy, meansb);
    mega_kernel<<<NB_SCL + NB_NSD + NB_CSUM, 256, 0, stream>>>(
        featb, meansb, featn, labels, xx, yy, out, pm, pl, bottom, csum);
    cemp_kernel<<<2048, 256, 0, stream>>>(featn, meansn, csum, labels, pm, pl, out,
                                          m_row, posr, ce_row);
    final_kernel<<<1, 256, 0, stream>>>(bottom, posr, labels, counts, ce_row, m_row,
                                        diag, xx, out + (size_t)BN * CN);
}

// Round 9
// 157.649 us; speedup vs baseline: 1.1049x; 1.1049x over previous
//
#include <hip/hip_runtime.h>
#include <math.h>

#define BN 8192
#define CN 1000
#define DN 128
#define INVT (1.0f/0.3f)
#define EXP2C 4.80898346962988f   // (1/0.3) * log2(e)
#define NEGBIG (-1e30f)           // finite sentinel (exp underflows to 0, no NaN)

typedef __bf16 bf16x8 __attribute__((ext_vector_type(8)));
typedef float  f32x4  __attribute__((ext_vector_type(4)));

// ws layout in floats
#define F_FEATN  0          // 8192*128
#define F_MEANSN 1048576    // 1000*128
#define F_XX     1176576    // 8192
#define F_YY     1184768    // 1000
#define F_DIAG   1185768    // 8192
#define F_FEATB  1193960    // 8192*128 bf16
#define F_MEANSB 1718248    // 1024*128 bf16 (raw, zero-padded)
#define F_CEROW  1783784    // 8192 (unused spare)
#define F_MROW   1791976    // 8192 (unused spare)
#define F_POSR   1800168    // 8192 (unused spare)
#define F_PL     1808360    // 4*8192 CE partial sums
#define F_BOT    1841128    // 8192   -- zeroed region start
#define F_CNT    1849320    // 1000 ints
#define F_CSUM   1850320    // 1000*128
#define F_RED    1978320    // 4 loss accumulators (sp, nv, ce, mg)

// mega-kernel block ranges (LDS-free; state fits 128 regs -> 4+ waves/SIMD)
#define NB_SCL  544   // 2176 waves: 32 i-rows x <=16 triangular 32-col j-tiles
#define NB_NSD  256   // 1024 waves: 32 rows x 256 cols, direct exp-sum (bounded logits)
#define NB_CSUM 256

// -------- feat: L2-normalize + bf16 copy + diag + label histogram --------
__global__ void norm_feat(const float* __restrict__ src, float* __restrict__ dst,
                          float* __restrict__ sq, __bf16* __restrict__ dstb,
                          float* __restrict__ diag, const int* __restrict__ labels,
                          int* __restrict__ counts) {
    int row = blockIdx.x * 4 + (threadIdx.x >> 6);
    int lane = threadIdx.x & 63;
    float f0 = src[row * DN + lane];
    float f1 = src[row * DN + 64 + lane];
    float ss = f0 * f0 + f1 * f1;
    #pragma unroll
    for (int o = 32; o > 0; o >>= 1) ss += __shfl_xor(ss, o);
    float inv = 1.0f / fmaxf(sqrtf(ss), 1e-12f);
    float n0 = f0 * inv, n1 = f1 * inv;
    dst[row * DN + lane] = n0;
    dst[row * DN + 64 + lane] = n1;
    __bf16 b0 = (__bf16)n0, b1 = (__bf16)n1;
    dstb[row * DN + lane] = b0;
    dstb[row * DN + 64 + lane] = b1;
    float fb0 = (float)b0, fb1 = (float)b1;
    float sb = fb0 * fb0 + fb1 * fb1;
    #pragma unroll
    for (int o = 32; o > 0; o >>= 1) sb += __shfl_xor(sb, o);
    if (lane == 0) {
        diag[row] = sb;
        sq[row] = ss * inv * inv;
        atomicAdd(&counts[labels[row]], 1);
    }
}

// -------- means: normalize (fp32) + yy + raw-bf16 copy padded to 1024 rows --------
__global__ void norm_means(const float* __restrict__ src, float* __restrict__ dst,
                           float* __restrict__ sq, __bf16* __restrict__ dstb) {
    int row = blockIdx.x * 4 + (threadIdx.x >> 6);   // 0..1023
    int lane = threadIdx.x & 63;
    float f0 = (row < CN) ? src[row * DN + lane] : 0.f;
    float f1 = (row < CN) ? src[row * DN + 64 + lane] : 0.f;
    dstb[row * DN + lane] = (__bf16)f0;
    dstb[row * DN + 64 + lane] = (__bf16)f1;
    if (row >= CN) return;
    float ss = f0 * f0 + f1 * f1;
    #pragma unroll
    for (int o = 32; o > 0; o >>= 1) ss += __shfl_xor(ss, o);
    float inv = 1.0f / fmaxf(sqrtf(ss), 1e-12f);
    dst[row * DN + lane] = f0 * inv;
    dst[row * DN + 64 + lane] = f1 * inv;
    if (lane == 0) sq[row] = ss;
}

// load 2 B-fragments (one k-chunk of a 32-col tile) straight from global/L2
__device__ __forceinline__ void loadB2(bf16x8* b, const uint4* __restrict__ src,
                                       int j0, int kk, int l15, int q) {
    #pragma unroll
    for (int jj = 0; jj < 2; jj++)
        b[jj] = *(const bf16x8*)&src[(size_t)(j0 + jj * 16 + l15) * 16 + kk * 4 + q];
}

// -------- mega kernel (LDS-free): [0,544) scl-tri | [544,800) nsd | [800,1056) csum --------
__global__ __launch_bounds__(256, 4) void mega_kernel(
        const __bf16* __restrict__ featb, const __bf16* __restrict__ meansb,
        const float* __restrict__ featn, const int* __restrict__ labels,
        const float* __restrict__ xx, const float* __restrict__ yy,
        float* __restrict__ out, float* __restrict__ pl,
        float* __restrict__ bottom, float* __restrict__ csum) {
    int bx = blockIdx.x;
    int tid = threadIdx.x;
    int lane = tid & 63, w = tid >> 6;
    int q = lane >> 4, l15 = lane & 15;

    if (bx < NB_SCL) {
        // ---- SCL: wave = 32 i-rows x <=16 triangular 32-col j-tiles ----
        int cid = bx * 4 + w;                 // 0..2175
        int g = 0;
        while (cid >= 16 * (16 - g)) { cid -= 16 * (16 - g); ++g; }
        int per = 16 - g, io = 0;
        while (cid >= per) { cid -= per; ++io; }
        int I = 16 * g + io;                  // 32-row i-block 0..255
        int J0 = I + 16 * cid;                // first 32-col j-tile
        int jend = min(J0 + 16, 256);
        int i0 = I * 32;
        const uint4* fv = (const uint4*)featb;

        bf16x8 af[2][4];
        #pragma unroll
        for (int ii = 0; ii < 2; ii++)
            #pragma unroll
            for (int kk = 0; kk < 4; kk++)
                af[ii][kk] = *(const bf16x8*)&fv[(size_t)(i0 + ii * 16 + l15) * 16 + kk * 4 + q];
        float bs[2][4] = {};

        bf16x8 b[2][2];
        loadB2(b[0], fv, J0 * 32, 0, l15, q);
        for (int J = J0; J < jend; J++) {
            int j0 = J * 32;
            int jn = (J + 1 < jend) ? (J + 1) * 32 : j0;
            f32x4 acc[2][2];
            #pragma unroll
            for (int ii = 0; ii < 2; ii++)
                #pragma unroll
                for (int jj = 0; jj < 2; jj++) acc[ii][jj] = (f32x4){0.f, 0.f, 0.f, 0.f};
            #pragma unroll
            for (int kk = 0; kk < 4; kk++) {
                if (kk < 3) loadB2(b[(kk + 1) & 1], fv, j0, kk + 1, l15, q);
                else        loadB2(b[0], fv, jn, 0, l15, q);   // next visit's kk=0
                #pragma unroll
                for (int ii = 0; ii < 2; ii++)
                    #pragma unroll
                    for (int jj = 0; jj < 2; jj++)
                        acc[ii][jj] = __builtin_amdgcn_mfma_f32_16x16x32_bf16(
                            af[ii][kk], b[kk & 1][jj], acc[ii][jj], 0, 0, 0);
            }
            float cp[2] = {0.f, 0.f};
            #pragma unroll
            for (int ii = 0; ii < 2; ii++)
                #pragma unroll
                for (int jj = 0; jj < 2; jj++)
                    #pragma unroll
                    for (int r4 = 0; r4 < 4; r4++) {
                        float e = exp2f(acc[ii][jj][r4] * EXP2C);
                        bs[ii][r4] += e;
                        cp[jj] += e;
                    }
            if (J != I) {      // mirror: column sums -> bottom[j] (skip diagonal tile)
                #pragma unroll
                for (int jj = 0; jj < 2; jj++) {
                    float c = cp[jj];
                    c += __shfl_xor(c, 16);
                    c += __shfl_xor(c, 32);
                    if (lane < 16)
                        atomicAdd(&bottom[j0 + jj * 16 + l15], c);
                }
            }
        }
        #pragma unroll
        for (int ii = 0; ii < 2; ii++)
            #pragma unroll
            for (int r4 = 0; r4 < 4; r4++) {
                float bsum = bs[ii][r4];
                #pragma unroll
                for (int o = 8; o > 0; o >>= 1) bsum += __shfl_xor(bsum, o);
                if (l15 == 0) atomicAdd(&bottom[i0 + ii * 16 + q * 4 + r4], bsum);
            }

    } else if (bx < NB_SCL + NB_NSD) {
        // ---- NSD: wave = 32 rows x 256 cols. Logits bounded (~[-11,1]) ->
        //      direct exp-sum, NO online max (fewer regs + fewer exps) ----
        int wid = (bx - NB_SCL) * 4 + w;      // 0..1023
        int ib = wid >> 2, qtr = wid & 3;
        int i0 = ib * 32;
        const uint4* fv = (const uint4*)featb;
        const uint4* mv = (const uint4*)meansb;
        bf16x8 af[2][4];
        #pragma unroll
        for (int ii = 0; ii < 2; ii++)
            #pragma unroll
            for (int kk = 0; kk < 4; kk++)
                af[ii][kk] = *(const bf16x8*)&fv[(size_t)(i0 + ii * 16 + l15) * 16 + kk * 4 + q];
        float srow[2][4] = {}, xa[2][4];
        int la[2][4];
        #pragma unroll
        for (int ii = 0; ii < 2; ii++) {
            int rbase = i0 + ii * 16 + q * 4;
            int4 lv = ((const int4*)labels)[rbase >> 2];
            float4 xv = ((const float4*)xx)[rbase >> 2];
            la[ii][0] = lv.x; la[ii][1] = lv.y; la[ii][2] = lv.z; la[ii][3] = lv.w;
            xa[ii][0] = xv.x; xa[ii][1] = xv.y; xa[ii][2] = xv.z; xa[ii][3] = xv.w;
        }
        bf16x8 b[2][2];
        loadB2(b[0], mv, qtr * 256, 0, l15, q);
        for (int s = 0; s < 8; s++) {
            int j0 = qtr * 256 + s * 32;
            int jn = (s < 7) ? j0 + 32 : j0;
            f32x4 acc[2][2];
            #pragma unroll
            for (int ii = 0; ii < 2; ii++)
                #pragma unroll
                for (int jj = 0; jj < 2; jj++) acc[ii][jj] = (f32x4){0.f, 0.f, 0.f, 0.f};
            #pragma unroll
            for (int kk = 0; kk < 4; kk++) {
                if (kk < 3) loadB2(b[(kk + 1) & 1], mv, j0, kk + 1, l15, q);
                else        loadB2(b[0], mv, jn, 0, l15, q);
                #pragma unroll
                for (int ii = 0; ii < 2; ii++)
                    #pragma unroll
                    for (int jj = 0; jj < 2; jj++)
                        acc[ii][jj] = __builtin_amdgcn_mfma_f32_16x16x32_bf16(
                            af[ii][kk], b[kk & 1][jj], acc[ii][jj], 0, 0, 0);
            }
            int c0 = j0 + l15, c1 = j0 + 16 + l15;
            float yv0 = (c0 < CN) ? yy[c0] : 0.f;
            float yv1 = (c1 < CN) ? yy[c1] : 0.f;
            #pragma unroll
            for (int ii = 0; ii < 2; ii++)
                #pragma unroll
                for (int r4 = 0; r4 < 4; r4++) {
                    int ig = i0 + ii * 16 + q * 4 + r4;
                    float v0 = -0.5f * (xa[ii][r4] - 2.f * acc[ii][0][r4] + yv0);
                    float v1 = -0.5f * (xa[ii][r4] - 2.f * acc[ii][1][r4] + yv1);
                    if (c0 < CN) out[(size_t)ig * CN + c0] = v0;
                    if (c1 < CN) out[(size_t)ig * CN + c1] = v1;
                    float l0 = (c0 == la[ii][r4]) ? 1.5f * v0 : v0;
                    float l1 = (c1 == la[ii][r4]) ? 1.5f * v1 : v1;
                    if (c0 >= CN) l0 = NEGBIG;   // exp underflows to exactly 0
                    if (c1 >= CN) l1 = NEGBIG;
                    srow[ii][r4] += __expf(l0) + __expf(l1);
                }
        }
        #pragma unroll
        for (int ii = 0; ii < 2; ii++)
            #pragma unroll
            for (int r4 = 0; r4 < 4; r4++) {
                float s2 = srow[ii][r4];
                #pragma unroll
                for (int o = 8; o > 0; o >>= 1) s2 += __shfl_xor(s2, o);
                if (l15 == 0) {
                    int ig = i0 + ii * 16 + q * 4 + r4;
                    pl[qtr * BN + ig] = s2;
                }
            }

    } else {
        // ---- csum: class-sum vectors via atomics ----
        int b2 = bx - NB_SCL - NB_NSD;
        for (int idx = b2 * 256 + tid; idx < BN * DN; idx += NB_CSUM * 256) {
            int row = idx >> 7, d = idx & 127;
            atomicAdd(&csum[labels[row] * DN + d], featn[idx]);
        }
    }
}

// -------- fused per-row epilogue + full loss reduction (512 blocks x 16 rows) --------
__global__ void cemp_kernel(const float* __restrict__ featn, const float* __restrict__ meansn,
        const float* __restrict__ csum, const int* __restrict__ labels,
        const float* __restrict__ pl, const float* __restrict__ out,
        const float* __restrict__ bottom, const int* __restrict__ counts,
        const float* __restrict__ diag, const float* __restrict__ xx,
        float* __restrict__ red) {
    int tid = threadIdx.x;
    int lane = tid & 63, w = tid >> 6;
    float a_sp = 0.f, a_nv = 0.f, a_ce = 0.f, a_mg = 0.f;
    for (int pass = 0; pass < 4; pass++) {
        int row = blockIdx.x * 16 + pass * 4 + w;
        int lab = labels[row];
        float f0 = featn[row * DN + lane],  f1 = featn[row * DN + 64 + lane];
        float m0 = meansn[lab * DN + lane], m1 = meansn[lab * DN + 64 + lane];
        float c0 = csum[lab * DN + lane],   c1 = csum[lab * DN + 64 + lane];
        float d0 = f0 - m0, d1 = f1 - m1;
        float ss = d0 * d0 + d1 * d1;
        float pp = f0 * c0 + f1 * c1;
        #pragma unroll
        for (int o = 32; o > 0; o >>= 1) {
            ss += __shfl_xor(ss, o);
            pp += __shfl_xor(pp, o);
        }
        if (lane == 0) {
            float S = 0.f;
            #pragma unroll
            for (int k = 0; k < 4; k++) S += pl[k * BN + row];
            a_ce += logf(S) - 1.5f * out[(size_t)row * CN + lab];
            a_mg += ss;
            float bot = bottom[row] - __expf(diag[row] * INVT);  // exclude j==i
            float pv = (pp - xx[row]) * INVT;                    // exclude j==i
            int c = counts[lab] - 1;
            if (c > 0) {
                a_sp += pv / (float)c - logf(bot);
                a_nv += 1.f;
            }
        }
    }
    __shared__ float r4[4][4];
    if (lane == 0) { r4[w][0] = a_sp; r4[w][1] = a_nv; r4[w][2] = a_ce; r4[w][3] = a_mg; }
    __syncthreads();
    if (tid < 4)
        atomicAdd(&red[tid], r4[0][tid] + r4[1][tid] + r4[2][tid] + r4[3][tid]);
}

__global__ void final_fin(const float* __restrict__ red, float* __restrict__ loss_out) {
    float SP = red[0], NV = red[1], CE = red[2], MG = red[3];
    float scl = -SP / fmaxf(NV, 1.f);
    loss_out[0] = 0.9f * (CE / (float)BN) + 0.1f * scl + 0.5f * (MG / (2.f * (float)BN));
}

extern "C" void kernel_launch(void* const* d_in, const int* in_sizes, int n_in,
                              void* d_out, int out_size, void* d_ws, size_t ws_size,
                              hipStream_t stream) {
    const float* feat   = (const float*)d_in[0];
    const int*   labels = (const int*)d_in[1];
    const float* means  = (const float*)d_in[2];
    float* out = (float*)d_out;
    float* ws  = (float*)d_ws;

    float*  featn  = ws + F_FEATN;
    float*  meansn = ws + F_MEANSN;
    float*  xx     = ws + F_XX;
    float*  yy     = ws + F_YY;
    float*  diag   = ws + F_DIAG;
    __bf16* featb  = (__bf16*)(ws + F_FEATB);
    __bf16* meansb = (__bf16*)(ws + F_MEANSB);
    float*  pl     = ws + F_PL;
    float*  bottom = ws + F_BOT;
    int*    counts = (int*)(ws + F_CNT);
    float*  csum   = ws + F_CSUM;
    float*  red    = ws + F_RED;

    // zero bottom + counts + csum + red (contiguous)
    hipMemsetAsync(ws + F_BOT, 0, (size_t)(8192 + 1000 + 128000 + 4) * sizeof(float), stream);

    norm_feat<<<2048, 256, 0, stream>>>(feat, featn, xx, featb, diag, labels, counts);
    norm_means<<<256, 256, 0, stream>>>(means, meansn, yy, meansb);
    mega_kernel<<<NB_SCL + NB_NSD + NB_CSUM, 256, 0, stream>>>(
        featb, meansb, featn, labels, xx, yy, out, pl, bottom, csum);
    cemp_kernel<<<512, 256, 0, stream>>>(featn, meansn, csum, labels, pl, out,
                                         bottom, counts, diag, xx, red);
    final_fin<<<1, 1, 0, stream>>>(red, out + (size_t)BN * CN);
}

// Round 10
// 146.734 us; speedup vs baseline: 1.1871x; 1.0744x over previous
//
#include <hip/hip_runtime.h>
#include <math.h>

#define BN 8192
#define CN 1000
#define DN 128
#define INVT (1.0f/0.3f)
#define EXP2C 4.80898346962988f   // (1/0.3) * log2(e)
#define NEGBIG (-1e30f)           // finite sentinel (exp underflows to 0, no NaN)

typedef __bf16 bf16x8 __attribute__((ext_vector_type(8)));
typedef float  f32x4  __attribute__((ext_vector_type(4)));

// ws layout in floats
#define F_FEATN  0          // 8192*128
#define F_MEANSN 1048576    // 1000*128
#define F_XX     1176576    // 8192
#define F_YY     1184768    // 1000
#define F_DIAG   1185768    // 8192
#define F_FEATB  1193960    // 8192*128 bf16
#define F_MEANSB 1718248    // 1024*128 bf16 (raw, zero-padded)
#define F_PL     1808360    // 4*8192 CE partial sums
#define F_BOT    1841128    // 8192   -- zeroed region start
#define F_CNT    1849320    // 1000 ints
#define F_CSUM   1850320    // 1000*128
#define F_RED    1978320    // 4 loss accumulators (sp, nv, ce, mg)

// mega-kernel block ranges (LDS-free)
#define NB_SCL  544   // 2176 waves: 32 i-rows x <=16 triangular 32-col j-tiles
#define NB_NSD  256   // 1024 waves: 32 rows x 256 cols, direct exp-sum (bounded logits)
#define NB_CSUM 256

// -------- feat: L2-normalize + bf16 copy + diag + label histogram --------
__global__ void norm_feat(const float* __restrict__ src, float* __restrict__ dst,
                          float* __restrict__ sq, __bf16* __restrict__ dstb,
                          float* __restrict__ diag, const int* __restrict__ labels,
                          int* __restrict__ counts) {
    int row = blockIdx.x * 4 + (threadIdx.x >> 6);
    int lane = threadIdx.x & 63;
    float f0 = src[row * DN + lane];
    float f1 = src[row * DN + 64 + lane];
    float ss = f0 * f0 + f1 * f1;
    #pragma unroll
    for (int o = 32; o > 0; o >>= 1) ss += __shfl_xor(ss, o);
    float inv = 1.0f / fmaxf(sqrtf(ss), 1e-12f);
    float n0 = f0 * inv, n1 = f1 * inv;
    dst[row * DN + lane] = n0;
    dst[row * DN + 64 + lane] = n1;
    __bf16 b0 = (__bf16)n0, b1 = (__bf16)n1;
    dstb[row * DN + lane] = b0;
    dstb[row * DN + 64 + lane] = b1;
    float fb0 = (float)b0, fb1 = (float)b1;
    float sb = fb0 * fb0 + fb1 * fb1;
    #pragma unroll
    for (int o = 32; o > 0; o >>= 1) sb += __shfl_xor(sb, o);
    if (lane == 0) {
        diag[row] = sb;
        sq[row] = ss * inv * inv;
        atomicAdd(&counts[labels[row]], 1);
    }
}

// -------- means: normalize (fp32) + yy + raw-bf16 copy padded to 1024 rows --------
__global__ void norm_means(const float* __restrict__ src, float* __restrict__ dst,
                           float* __restrict__ sq, __bf16* __restrict__ dstb) {
    int row = blockIdx.x * 4 + (threadIdx.x >> 6);   // 0..1023
    int lane = threadIdx.x & 63;
    float f0 = (row < CN) ? src[row * DN + lane] : 0.f;
    float f1 = (row < CN) ? src[row * DN + 64 + lane] : 0.f;
    dstb[row * DN + lane] = (__bf16)f0;
    dstb[row * DN + 64 + lane] = (__bf16)f1;
    if (row >= CN) return;
    float ss = f0 * f0 + f1 * f1;
    #pragma unroll
    for (int o = 32; o > 0; o >>= 1) ss += __shfl_xor(ss, o);
    float inv = 1.0f / fmaxf(sqrtf(ss), 1e-12f);
    dst[row * DN + lane] = f0 * inv;
    dst[row * DN + 64 + lane] = f1 * inv;
    if (lane == 0) sq[row] = ss;
}

// load 2 B-fragments (one k-chunk of a 32-col tile) straight from global/L2
__device__ __forceinline__ void loadB2(bf16x8* b, const uint4* __restrict__ src,
                                       int j0, int kk, int l15, int q) {
    #pragma unroll
    for (int jj = 0; jj < 2; jj++)
        b[jj] = *(const bf16x8*)&src[(size_t)(j0 + jj * 16 + l15) * 16 + kk * 4 + q];
}

// -------- mega kernel (LDS-free): [0,544) scl-tri | [544,800) nsd | [800,1056) csum
// (256,3): 170 unified regs/wave -- fits the ~105-arch + 16-acc state with NO spill,
// 3 waves/SIMD for latency hiding. (256,4)=128 regs provably spills (r8/r9). --------
__global__ __launch_bounds__(256, 3) void mega_kernel(
        const __bf16* __restrict__ featb, const __bf16* __restrict__ meansb,
        const float* __restrict__ featn, const int* __restrict__ labels,
        const float* __restrict__ xx, const float* __restrict__ yy,
        float* __restrict__ out, float* __restrict__ pl,
        float* __restrict__ bottom, float* __restrict__ csum) {
    int bx = blockIdx.x;
    int tid = threadIdx.x;
    int lane = tid & 63, w = tid >> 6;
    int q = lane >> 4, l15 = lane & 15;

    if (bx < NB_SCL) {
        // ---- SCL: wave = 32 i-rows x <=16 triangular 32-col j-tiles ----
        int cid = bx * 4 + w;                 // 0..2175
        int g = 0;
        while (cid >= 16 * (16 - g)) { cid -= 16 * (16 - g); ++g; }
        int per = 16 - g, io = 0;
        while (cid >= per) { cid -= per; ++io; }
        int I = 16 * g + io;                  // 32-row i-block 0..255
        int J0 = I + 16 * cid;                // first 32-col j-tile
        int jend = min(J0 + 16, 256);
        int i0 = I * 32;
        const uint4* fv = (const uint4*)featb;

        bf16x8 af[2][4];
        #pragma unroll
        for (int ii = 0; ii < 2; ii++)
            #pragma unroll
            for (int kk = 0; kk < 4; kk++)
                af[ii][kk] = *(const bf16x8*)&fv[(size_t)(i0 + ii * 16 + l15) * 16 + kk * 4 + q];
        float bs[2][4] = {};

        bf16x8 b[2][2];
        loadB2(b[0], fv, J0 * 32, 0, l15, q);
        for (int J = J0; J < jend; J++) {
            int j0 = J * 32;
            int jn = (J + 1 < jend) ? (J + 1) * 32 : j0;
            f32x4 acc[2][2];
            #pragma unroll
            for (int ii = 0; ii < 2; ii++)
                #pragma unroll
                for (int jj = 0; jj < 2; jj++) acc[ii][jj] = (f32x4){0.f, 0.f, 0.f, 0.f};
            #pragma unroll
            for (int kk = 0; kk < 4; kk++) {
                if (kk < 3) loadB2(b[(kk + 1) & 1], fv, j0, kk + 1, l15, q);
                else        loadB2(b[0], fv, jn, 0, l15, q);   // next visit's kk=0
                #pragma unroll
                for (int ii = 0; ii < 2; ii++)
                    #pragma unroll
                    for (int jj = 0; jj < 2; jj++)
                        acc[ii][jj] = __builtin_amdgcn_mfma_f32_16x16x32_bf16(
                            af[ii][kk], b[kk & 1][jj], acc[ii][jj], 0, 0, 0);
            }
            float cp[2] = {0.f, 0.f};
            #pragma unroll
            for (int ii = 0; ii < 2; ii++)
                #pragma unroll
                for (int jj = 0; jj < 2; jj++)
                    #pragma unroll
                    for (int r4 = 0; r4 < 4; r4++) {
                        float e = exp2f(acc[ii][jj][r4] * EXP2C);
                        bs[ii][r4] += e;
                        cp[jj] += e;
                    }
            if (J != I) {      // mirror: column sums -> bottom[j] (skip diagonal tile)
                #pragma unroll
                for (int jj = 0; jj < 2; jj++) {
                    float c = cp[jj];
                    c += __shfl_xor(c, 16);
                    c += __shfl_xor(c, 32);
                    if (lane < 16)
                        atomicAdd(&bottom[j0 + jj * 16 + l15], c);
                }
            }
        }
        #pragma unroll
        for (int ii = 0; ii < 2; ii++)
            #pragma unroll
            for (int r4 = 0; r4 < 4; r4++) {
                float bsum = bs[ii][r4];
                #pragma unroll
                for (int o = 8; o > 0; o >>= 1) bsum += __shfl_xor(bsum, o);
                if (l15 == 0) atomicAdd(&bottom[i0 + ii * 16 + q * 4 + r4], bsum);
            }

    } else if (bx < NB_SCL + NB_NSD) {
        // ---- NSD: wave = 32 rows x 256 cols. Logits bounded (~[-11,1]) ->
        //      direct exp-sum, NO online max ----
        int wid = (bx - NB_SCL) * 4 + w;      // 0..1023
        int ib = wid >> 2, qtr = wid & 3;
        int i0 = ib * 32;
        const uint4* fv = (const uint4*)featb;
        const uint4* mv = (const uint4*)meansb;
        bf16x8 af[2][4];
        #pragma unroll
        for (int ii = 0; ii < 2; ii++)
            #pragma unroll
            for (int kk = 0; kk < 4; kk++)
                af[ii][kk] = *(const bf16x8*)&fv[(size_t)(i0 + ii * 16 + l15) * 16 + kk * 4 + q];
        float srow[2][4] = {}, xa[2][4];
        int la[2][4];
        #pragma unroll
        for (int ii = 0; ii < 2; ii++) {
            int rbase = i0 + ii * 16 + q * 4;
            int4 lv = ((const int4*)labels)[rbase >> 2];
            float4 xv = ((const float4*)xx)[rbase >> 2];
            la[ii][0] = lv.x; la[ii][1] = lv.y; la[ii][2] = lv.z; la[ii][3] = lv.w;
            xa[ii][0] = xv.x; xa[ii][1] = xv.y; xa[ii][2] = xv.z; xa[ii][3] = xv.w;
        }
        bf16x8 b[2][2];
        loadB2(b[0], mv, qtr * 256, 0, l15, q);
        for (int s = 0; s < 8; s++) {
            int j0 = qtr * 256 + s * 32;
            int jn = (s < 7) ? j0 + 32 : j0;
            f32x4 acc[2][2];
            #pragma unroll
            for (int ii = 0; ii < 2; ii++)
                #pragma unroll
                for (int jj = 0; jj < 2; jj++) acc[ii][jj] = (f32x4){0.f, 0.f, 0.f, 0.f};
            #pragma unroll
            for (int kk = 0; kk < 4; kk++) {
                if (kk < 3) loadB2(b[(kk + 1) & 1], mv, j0, kk + 1, l15, q);
                else        loadB2(b[0], mv, jn, 0, l15, q);
                #pragma unroll
                for (int ii = 0; ii < 2; ii++)
                    #pragma unroll
                    for (int jj = 0; jj < 2; jj++)
                        acc[ii][jj] = __builtin_amdgcn_mfma_f32_16x16x32_bf16(
                            af[ii][kk], b[kk & 1][jj], acc[ii][jj], 0, 0, 0);
            }
            int c0 = j0 + l15, c1 = j0 + 16 + l15;
            float yv0 = (c0 < CN) ? yy[c0] : 0.f;
            float yv1 = (c1 < CN) ? yy[c1] : 0.f;
            #pragma unroll
            for (int ii = 0; ii < 2; ii++)
                #pragma unroll
                for (int r4 = 0; r4 < 4; r4++) {
                    int ig = i0 + ii * 16 + q * 4 + r4;
                    float v0 = -0.5f * (xa[ii][r4] - 2.f * acc[ii][0][r4] + yv0);
                    float v1 = -0.5f * (xa[ii][r4] - 2.f * acc[ii][1][r4] + yv1);
                    if (c0 < CN) out[(size_t)ig * CN + c0] = v0;
                    if (c1 < CN) out[(size_t)ig * CN + c1] = v1;
                    float l0 = (c0 == la[ii][r4]) ? 1.5f * v0 : v0;
                    float l1 = (c1 == la[ii][r4]) ? 1.5f * v1 : v1;
                    if (c0 >= CN) l0 = NEGBIG;   // exp underflows to exactly 0
                    if (c1 >= CN) l1 = NEGBIG;
                    srow[ii][r4] += __expf(l0) + __expf(l1);
                }
        }
        #pragma unroll
        for (int ii = 0; ii < 2; ii++)
            #pragma unroll
            for (int r4 = 0; r4 < 4; r4++) {
                float s2 = srow[ii][r4];
                #pragma unroll
                for (int o = 8; o > 0; o >>= 1) s2 += __shfl_xor(s2, o);
                if (l15 == 0) {
                    int ig = i0 + ii * 16 + q * 4 + r4;
                    pl[qtr * BN + ig] = s2;
                }
            }

    } else {
        // ---- csum: class-sum vectors via atomics ----
        int b2 = bx - NB_SCL - NB_NSD;
        for (int idx = b2 * 256 + tid; idx < BN * DN; idx += NB_CSUM * 256) {
            int row = idx >> 7, d = idx & 127;
            atomicAdd(&csum[labels[row] * DN + d], featn[idx]);
        }
    }
}

// -------- fused per-row epilogue + full loss reduction (512 blocks x 16 rows) --------
__global__ void cemp_kernel(const float* __restrict__ featn, const float* __restrict__ meansn,
        const float* __restrict__ csum, const int* __restrict__ labels,
        const float* __restrict__ pl, const float* __restrict__ out,
        const float* __restrict__ bottom, const int* __restrict__ counts,
        const float* __restrict__ diag, const float* __restrict__ xx,
        float* __restrict__ red) {
    int tid = threadIdx.x;
    int lane = tid & 63, w = tid >> 6;
    float a_sp = 0.f, a_nv = 0.f, a_ce = 0.f, a_mg = 0.f;
    for (int pass = 0; pass < 4; pass++) {
        int row = blockIdx.x * 16 + pass * 4 + w;
        int lab = labels[row];
        float f0 = featn[row * DN + lane],  f1 = featn[row * DN + 64 + lane];
        float m0 = meansn[lab * DN + lane], m1 = meansn[lab * DN + 64 + lane];
        float c0 = csum[lab * DN + lane],   c1 = csum[lab * DN + 64 + lane];
        float d0 = f0 - m0, d1 = f1 - m1;
        float ss = d0 * d0 + d1 * d1;
        float pp = f0 * c0 + f1 * c1;
        #pragma unroll
        for (int o = 32; o > 0; o >>= 1) {
            ss += __shfl_xor(ss, o);
            pp += __shfl_xor(pp, o);
        }
        if (lane == 0) {
            float S = 0.f;
            #pragma unroll
            for (int k = 0; k < 4; k++) S += pl[k * BN + row];
            a_ce += logf(S) - 1.5f * out[(size_t)row * CN + lab];
            a_mg += ss;
            float bot = bottom[row] - __expf(diag[row] * INVT);  // exclude j==i
            float pv = (pp - xx[row]) * INVT;                    // exclude j==i
            int c = counts[lab] - 1;
            if (c > 0) {
                a_sp += pv / (float)c - logf(bot);
                a_nv += 1.f;
            }
        }
    }
    __shared__ float r4[4][4];
    if (lane == 0) { r4[w][0] = a_sp; r4[w][1] = a_nv; r4[w][2] = a_ce; r4[w][3] = a_mg; }
    __syncthreads();
    if (tid < 4)
        atomicAdd(&red[tid], r4[0][tid] + r4[1][tid] + r4[2][tid] + r4[3][tid]);
}

__global__ void final_fin(const float* __restrict__ red, float* __restrict__ loss_out) {
    float SP = red[0], NV = red[1], CE = red[2], MG = red[3];
    float scl = -SP / fmaxf(NV, 1.f);
    loss_out[0] = 0.9f * (CE / (float)BN) + 0.1f * scl + 0.5f * (MG / (2.f * (float)BN));
}

extern "C" void kernel_launch(void* const* d_in, const int* in_sizes, int n_in,
                              void* d_out, int out_size, void* d_ws, size_t ws_size,
                              hipStream_t stream) {
    const float* feat   = (const float*)d_in[0];
    const int*   labels = (const int*)d_in[1];
    const float* means  = (const float*)d_in[2];
    float* out = (float*)d_out;
    float* ws  = (float*)d_ws;

    float*  featn  = ws + F_FEATN;
    float*  meansn = ws + F_MEANSN;
    float*  xx     = ws + F_XX;
    float*  yy     = ws + F_YY;
    float*  diag   = ws + F_DIAG;
    __bf16* featb  = (__bf16*)(ws + F_FEATB);
    __bf16* meansb = (__bf16*)(ws + F_MEANSB);
    float*  pl     = ws + F_PL;
    float*  bottom = ws + F_BOT;
    int*    counts = (int*)(ws + F_CNT);
    float*  csum   = ws + F_CSUM;
    float*  red    = ws + F_RED;

    // zero bottom + counts + csum + red (contiguous)
    hipMemsetAsync(ws + F_BOT, 0, (size_t)(8192 + 1000 + 128000 + 4) * sizeof(float), stream);

    norm_feat<<<2048, 256, 0, stream>>>(feat, featn, xx, featb, diag, labels, counts);
    norm_means<<<256, 256, 0, stream>>>(means, meansn, yy, meansb);
    mega_kernel<<<NB_SCL + NB_NSD + NB_CSUM, 256, 0, stream>>>(
        featb, meansb, featn, labels, xx, yy, out, pl, bottom, csum);
    cemp_kernel<<<512, 256, 0, stream>>>(featn, meansn, csum, labels, pl, out,
                                         bottom, counts, diag, xx, red);
    final_fin<<<1, 1, 0, stream>>>(red, out + (size_t)BN * CN);
}

// Round 11
// 128.717 us; speedup vs baseline: 1.3533x; 1.1400x over previous
//
#include <hip/hip_runtime.h>
#include <math.h>

#define BN 8192
#define CN 1000
#define DN 128
#define INVT (1.0f/0.3f)
#define EXP2C 4.80898346962988f   // (1/0.3) * log2(e)
#define NEGBIG (-1e30f)           // finite sentinel (exp underflows to 0, no NaN)

typedef __bf16 bf16x8 __attribute__((ext_vector_type(8)));
typedef float  f32x4  __attribute__((ext_vector_type(4)));

// ws layout in floats
#define F_FEATN  0          // 8192*128
#define F_MEANSN 1048576    // 1000*128
#define F_XX     1176576    // 8192
#define F_YY     1184768    // 1000
#define F_DIAG   1185768    // 8192
#define F_FEATB  1193960    // 8192*128 bf16
#define F_MEANSB 1718248    // 1024*128 bf16 (raw, zero-padded)
#define F_PL     1808360    // 16*8192 CE partial sums
#define F_BOT    1939432    // 8192   -- zeroed region start
#define F_CNT    1947624    // 1000 ints
#define F_CSUM   1948624    // 1000*128
#define F_RED    2076624    // 4 loss accumulators (sp, nv, ce, mg)

// mega-kernel block ranges (r5 structure: LDS-staged, (256,2))
#define NB_SCL  544   // triangular strips of <=4 128x128 tiles
#define NB_NSD  512   // 8 x 64 nsd 128x128 tiles
#define NB_CSUM 512

__device__ __forceinline__ void async16(const void* g, void* s) {
    __builtin_amdgcn_global_load_lds(
        (const __attribute__((address_space(1))) void*)g,
        (__attribute__((address_space(3))) void*)s, 16, 0, 0);
}

// -------- feat: L2-normalize + bf16 copy + diag + label histogram --------
__global__ void norm_feat(const float* __restrict__ src, float* __restrict__ dst,
                          float* __restrict__ sq, __bf16* __restrict__ dstb,
                          float* __restrict__ diag, const int* __restrict__ labels,
                          int* __restrict__ counts) {
    int row = blockIdx.x * 4 + (threadIdx.x >> 6);
    int lane = threadIdx.x & 63;
    float f0 = src[row * DN + lane];
    float f1 = src[row * DN + 64 + lane];
    float ss = f0 * f0 + f1 * f1;
    #pragma unroll
    for (int o = 32; o > 0; o >>= 1) ss += __shfl_xor(ss, o);
    float inv = 1.0f / fmaxf(sqrtf(ss), 1e-12f);
    float n0 = f0 * inv, n1 = f1 * inv;
    dst[row * DN + lane] = n0;
    dst[row * DN + 64 + lane] = n1;
    __bf16 b0 = (__bf16)n0, b1 = (__bf16)n1;
    dstb[row * DN + lane] = b0;
    dstb[row * DN + 64 + lane] = b1;
    float fb0 = (float)b0, fb1 = (float)b1;
    float sb = fb0 * fb0 + fb1 * fb1;
    #pragma unroll
    for (int o = 32; o > 0; o >>= 1) sb += __shfl_xor(sb, o);
    if (lane == 0) {
        diag[row] = sb;
        sq[row] = ss * inv * inv;
        atomicAdd(&counts[labels[row]], 1);
    }
}

// -------- means: normalize (fp32) + yy + raw-bf16 copy padded to 1024 rows --------
__global__ void norm_means(const float* __restrict__ src, float* __restrict__ dst,
                           float* __restrict__ sq, __bf16* __restrict__ dstb) {
    int row = blockIdx.x * 4 + (threadIdx.x >> 6);   // 0..1023
    int lane = threadIdx.x & 63;
    float f0 = (row < CN) ? src[row * DN + lane] : 0.f;
    float f1 = (row < CN) ? src[row * DN + 64 + lane] : 0.f;
    dstb[row * DN + lane] = (__bf16)f0;
    dstb[row * DN + 64 + lane] = (__bf16)f1;
    if (row >= CN) return;
    float ss = f0 * f0 + f1 * f1;
    #pragma unroll
    for (int o = 32; o > 0; o >>= 1) ss += __shfl_xor(ss, o);
    float inv = 1.0f / fmaxf(sqrtf(ss), 1e-12f);
    dst[row * DN + lane] = f0 * inv;
    dst[row * DN + 64 + lane] = f1 * inv;
    if (lane == 0) sq[row] = ss;
}

// stage a 128x128 bf16 tile into LDS, XOR-swizzled (register round-trip; nsd path)
__device__ __forceinline__ void stage128(uint4* sT, const uint4* __restrict__ src,
                                         int row0, int tid) {
    #pragma unroll
    for (int s = 0; s < 8; s++) {
        int c = tid + s * 256;
        int r = c >> 4, ch = c & 15;
        sT[r * 16 + (ch ^ (r & 7))] = src[(size_t)(row0 + r) * 16 + ch];
    }
}

// -------- mega kernel (r5 structure): [0,544) scl-tri | [544,1056) nsd | [1056,1568) csum --------
__global__ __launch_bounds__(256, 2) void mega_kernel(
        const __bf16* __restrict__ featb, const __bf16* __restrict__ meansb,
        const float* __restrict__ featn, const int* __restrict__ labels,
        const float* __restrict__ xx, const float* __restrict__ yy,
        float* __restrict__ out, float* __restrict__ pl,
        float* __restrict__ bottom, float* __restrict__ csum) {
    __shared__ uint4 sh[2][2048];
    int bx = blockIdx.x;
    int tid = threadIdx.x;
    int lane = tid & 63, w = tid >> 6;
    int q = lane >> 4, l15 = lane & 15;

    if (bx < NB_SCL) {
        // ---- SCL: triangular strip of <=4 128x128 tiles at row-block I ----
        int rem = bx, I = 0;
        while (true) { int ns = (64 - I + 3) >> 2; if (rem < ns) break; rem -= ns; ++I; }
        int J0 = I + rem * 4;
        int len = min(4, 64 - J0);
        int i0 = I * 128;
        const uint4* fv = (const uint4*)featb;
        int wrow = (w >> 1) * 64, wcol = (w & 1) * 64;

        bf16x8 af[4][4];
        #pragma unroll
        for (int ii = 0; ii < 4; ii++) {
            size_t r = (size_t)(i0 + wrow + ii * 16 + l15) * 16;
            #pragma unroll
            for (int kk = 0; kk < 4; kk++)
                af[ii][kk] = *(const bf16x8*)&fv[r + kk * 4 + q];
        }
        float bs[4][4] = {};

        auto stage = [&](int row0, int buf) {
            #pragma unroll
            for (int s = 0; s < 8; s++) {
                int rb = w * 32 + s * 4;
                int r = rb + q;
                async16(&fv[(size_t)(row0 + r) * 16 + (l15 ^ (r & 7))], &sh[buf][rb * 16]);
            }
        };

        stage(J0 * 128, 0);
        if (len > 1) stage(J0 * 128 + 128, 1);

        for (int t = 0; t < len; t++) {
            if (t + 1 < len) asm volatile("s_waitcnt vmcnt(8)" ::: "memory");
            else             asm volatile("s_waitcnt vmcnt(0)" ::: "memory");
            __builtin_amdgcn_s_barrier();
            const uint4* B = sh[t & 1];

            f32x4 acc[4][4];
            #pragma unroll
            for (int ii = 0; ii < 4; ii++)
                #pragma unroll
                for (int jj = 0; jj < 4; jj++) acc[ii][jj] = (f32x4){0.f, 0.f, 0.f, 0.f};
            #pragma unroll
            for (int kk = 0; kk < 4; kk++) {
                bf16x8 bfv[4];
                #pragma unroll
                for (int jj = 0; jj < 4; jj++) {
                    int r = wcol + jj * 16 + l15;
                    bfv[jj] = *(const bf16x8*)&B[r * 16 + ((kk * 4 + q) ^ (r & 7))];
                }
                #pragma unroll
                for (int ii = 0; ii < 4; ii++)
                    #pragma unroll
                    for (int jj = 0; jj < 4; jj++)
                        acc[ii][jj] = __builtin_amdgcn_mfma_f32_16x16x32_bf16(
                            af[ii][kk], bfv[jj], acc[ii][jj], 0, 0, 0);
            }

            int jt = (J0 + t) * 128;
            float cp[4] = {0.f, 0.f, 0.f, 0.f};
            #pragma unroll
            for (int ii = 0; ii < 4; ii++)
                #pragma unroll
                for (int jj = 0; jj < 4; jj++)
                    #pragma unroll
                    for (int r4 = 0; r4 < 4; r4++) {
                        float e = exp2f(acc[ii][jj][r4] * EXP2C);
                        bs[ii][r4] += e;
                        cp[jj] += e;
                    }
            if (J0 + t != I) {      // mirror contribution to bottom[j]
                #pragma unroll
                for (int jj = 0; jj < 4; jj++) {
                    float c = cp[jj];
                    c += __shfl_xor(c, 16);
                    c += __shfl_xor(c, 32);
                    if (lane < 16)
                        atomicAdd(&bottom[jt + wcol + jj * 16 + l15], c);
                }
            }
            __builtin_amdgcn_s_barrier();
            if (t + 2 < len) stage((J0 + t + 2) * 128, t & 1);
        }

        int ibase = i0 + wrow + q * 4;
        #pragma unroll
        for (int ii = 0; ii < 4; ii++)
            #pragma unroll
            for (int r4 = 0; r4 < 4; r4++) {
                float b = bs[ii][r4];
                #pragma unroll
                for (int o = 8; o > 0; o >>= 1) b += __shfl_xor(b, o);
                if (l15 == 0) atomicAdd(&bottom[ibase + ii * 16 + r4], b);
            }

    } else if (bx < NB_SCL + NB_NSD) {
        // ---- NSD (LDS-staged 128x128). Bounded logits -> direct exp-sum, no max ----
        int b = bx - NB_SCL;
        int i0 = (b >> 3) * 128, j0 = (b & 7) * 128;
        stage128(sh[0], (const uint4*)featb, i0, tid);
        stage128(sh[1], (const uint4*)meansb, j0, tid);
        __syncthreads();
        int wrow = (w >> 1) * 64, wcol = (w & 1) * 64;
        int ibase = i0 + wrow + q * 4;

        f32x4 acc[4][4];
        #pragma unroll
        for (int ii = 0; ii < 4; ii++)
            #pragma unroll
            for (int jj = 0; jj < 4; jj++) acc[ii][jj] = (f32x4){0.f, 0.f, 0.f, 0.f};
        #pragma unroll
        for (int kk = 0; kk < 4; kk++) {
            bf16x8 af[4], bfv[4];
            #pragma unroll
            for (int ii = 0; ii < 4; ii++) {
                int r = wrow + ii * 16 + l15;
                af[ii] = *(const bf16x8*)&sh[0][r * 16 + ((kk * 4 + q) ^ (r & 7))];
            }
            #pragma unroll
            for (int jj = 0; jj < 4; jj++) {
                int r = wcol + jj * 16 + l15;
                bfv[jj] = *(const bf16x8*)&sh[1][r * 16 + ((kk * 4 + q) ^ (r & 7))];
            }
            #pragma unroll
            for (int ii = 0; ii < 4; ii++)
                #pragma unroll
                for (int jj = 0; jj < 4; jj++)
                    acc[ii][jj] = __builtin_amdgcn_mfma_f32_16x16x32_bf16(
                        af[ii], bfv[jj], acc[ii][jj], 0, 0, 0);
        }
        int jg[4]; float yv[4];
        #pragma unroll
        for (int jj = 0; jj < 4; jj++) {
            jg[jj] = j0 + wcol + jj * 16 + l15;
            yv[jj] = (jg[jj] < CN) ? yy[jg[jj]] : 0.f;
        }
        int pslot = ((b & 7) * 2 + (w & 1)) * BN;
        #pragma unroll
        for (int ii = 0; ii < 4; ii++) {
            int rbase = ibase + ii * 16;
            float4 xv = ((const float4*)xx)[rbase >> 2];
            int4 lv = ((const int4*)labels)[rbase >> 2];
            float xa[4] = {xv.x, xv.y, xv.z, xv.w};
            int la[4] = {lv.x, lv.y, lv.z, lv.w};
            #pragma unroll
            for (int r4 = 0; r4 < 4; r4++) {
                int ig = rbase + r4;
                float s = 0.f;
                #pragma unroll
                for (int jj = 0; jj < 4; jj++) {
                    float v = -0.5f * (xa[r4] - 2.f * acc[ii][jj][r4] + yv[jj]);
                    bool ok = (jg[jj] < CN);
                    if (ok) out[(size_t)ig * CN + jg[jj]] = v;
                    float l = (jg[jj] == la[r4]) ? 1.5f * v : v;
                    s += ok ? __expf(l) : 0.f;
                }
                #pragma unroll
                for (int o = 8; o > 0; o >>= 1) s += __shfl_xor(s, o);
                if (l15 == 0) pl[pslot + ig] = s;
            }
        }

    } else {
        // ---- csum: class-sum vectors via atomics ----
        int b2 = bx - NB_SCL - NB_NSD;
        for (int idx = b2 * 256 + tid; idx < BN * DN; idx += NB_CSUM * 256) {
            int row = idx >> 7, d = idx & 127;
            atomicAdd(&csum[labels[row] * DN + d], featn[idx]);
        }
    }
}

// -------- fused per-row epilogue + full loss reduction (512 blocks x 16 rows) --------
__global__ void cemp_kernel(const float* __restrict__ featn, const float* __restrict__ meansn,
        const float* __restrict__ csum, const int* __restrict__ labels,
        const float* __restrict__ pl, const float* __restrict__ out,
        const float* __restrict__ bottom, const int* __restrict__ counts,
        const float* __restrict__ diag, const float* __restrict__ xx,
        float* __restrict__ red) {
    int tid = threadIdx.x;
    int lane = tid & 63, w = tid >> 6;
    float a_sp = 0.f, a_nv = 0.f, a_ce = 0.f, a_mg = 0.f;
    for (int pass = 0; pass < 4; pass++) {
        int row = blockIdx.x * 16 + pass * 4 + w;
        int lab = labels[row];
        float f0 = featn[row * DN + lane],  f1 = featn[row * DN + 64 + lane];
        float m0 = meansn[lab * DN + lane], m1 = meansn[lab * DN + 64 + lane];
        float c0 = csum[lab * DN + lane],   c1 = csum[lab * DN + 64 + lane];
        float d0 = f0 - m0, d1 = f1 - m1;
        float ss = d0 * d0 + d1 * d1;
        float pp = f0 * c0 + f1 * c1;
        #pragma unroll
        for (int o = 32; o > 0; o >>= 1) {
            ss += __shfl_xor(ss, o);
            pp += __shfl_xor(pp, o);
        }
        if (lane == 0) {
            float S = 0.f;
            #pragma unroll
            for (int k = 0; k < 16; k++) S += pl[k * BN + row];
            a_ce += logf(S) - 1.5f * out[(size_t)row * CN + lab];
            a_mg += ss;
            float bot = bottom[row] - __expf(diag[row] * INVT);  // exclude j==i
            float pv = (pp - xx[row]) * INVT;                    // exclude j==i
            int c = counts[lab] - 1;
            if (c > 0) {
                a_sp += pv / (float)c - logf(bot);
                a_nv += 1.f;
            }
        }
    }
    __shared__ float r4[4][4];
    if (lane == 0) { r4[w][0] = a_sp; r4[w][1] = a_nv; r4[w][2] = a_ce; r4[w][3] = a_mg; }
    __syncthreads();
    if (tid < 4)
        atomicAdd(&red[tid], r4[0][tid] + r4[1][tid] + r4[2][tid] + r4[3][tid]);
}

__global__ void final_fin(const float* __restrict__ red, float* __restrict__ loss_out) {
    float SP = red[0], NV = red[1], CE = red[2], MG = red[3];
    float scl = -SP / fmaxf(NV, 1.f);
    loss_out[0] = 0.9f * (CE / (float)BN) + 0.1f * scl + 0.5f * (MG / (2.f * (float)BN));
}

extern "C" void kernel_launch(void* const* d_in, const int* in_sizes, int n_in,
                              void* d_out, int out_size, void* d_ws, size_t ws_size,
                              hipStream_t stream) {
    const float* feat   = (const float*)d_in[0];
    const int*   labels = (const int*)d_in[1];
    const float* means  = (const float*)d_in[2];
    float* out = (float*)d_out;
    float* ws  = (float*)d_ws;

    float*  featn  = ws + F_FEATN;
    float*  meansn = ws + F_MEANSN;
    float*  xx     = ws + F_XX;
    float*  yy     = ws + F_YY;
    float*  diag   = ws + F_DIAG;
    __bf16* featb  = (__bf16*)(ws + F_FEATB);
    __bf16* meansb = (__bf16*)(ws + F_MEANSB);
    float*  pl     = ws + F_PL;
    float*  bottom = ws + F_BOT;
    int*    counts = (int*)(ws + F_CNT);
    float*  csum   = ws + F_CSUM;
    float*  red    = ws + F_RED;

    // zero bottom + counts + csum + red (contiguous)
    hipMemsetAsync(ws + F_BOT, 0, (size_t)(8192 + 1000 + 128000 + 4) * sizeof(float), stream);

    norm_feat<<<2048, 256, 0, stream>>>(feat, featn, xx, featb, diag, labels, counts);
    norm_means<<<256, 256, 0, stream>>>(means, meansn, yy, meansb);
    mega_kernel<<<NB_SCL + NB_NSD + NB_CSUM, 256, 0, stream>>>(
        featb, meansb, featn, labels, xx, yy, out, pl, bottom, csum);
    cemp_kernel<<<512, 256, 0, stream>>>(featn, meansn, csum, labels, pl, out,
                                         bottom, counts, diag, xx, red);
    final_fin<<<1, 1, 0, stream>>>(red, out + (size_t)BN * CN);
}

// Round 12
// 125.572 us; speedup vs baseline: 1.3872x; 1.0250x over previous
//
#include <hip/hip_runtime.h>
#include <math.h>

#define BN 8192
#define CN 1000
#define DN 128
#define INVT (1.0f/0.3f)
#define EXP2C 4.80898346962988f   // (1/0.3) * log2(e)

typedef __bf16 bf16x8 __attribute__((ext_vector_type(8)));
typedef float  f32x4  __attribute__((ext_vector_type(4)));

// ws layout in floats
#define F_FEATN  0          // 8192*128
#define F_MEANSN 1048576    // 1000*128
#define F_XX     1176576    // 8192
#define F_YY     1184768    // 1000
#define F_DIAG   1185768    // 8192
#define F_FEATB  1193960    // 8192*128 bf16
#define F_MEANSB 1718248    // 1024*128 bf16 (raw, zero-padded)
#define F_PL     1808360    // 16*8192 CE partial sums
#define F_BOT    1939432    // 8192   -- zeroed region start
#define F_CNT    1947624    // 1000 ints
#define F_CSUM   1948624    // 1000*128
#define F_RED    2076624    // 4 loss accumulators (sp, nv, ce, mg)

// mega-kernel block ranges: 64-row blocks, single 32KB LDS buffer, (256,3)
#define NB_SCL  576   // (a, strip): a=64-row block (128 of them), strips of <=8 j-tiles, J>=A=a/2
#define NB_NSD  1024  // 128 i-blocks(64 rows) x 8 j-tiles(128 cols)
#define NB_CSUM 512

__device__ __forceinline__ void async16(const void* g, void* s) {
    __builtin_amdgcn_global_load_lds(
        (const __attribute__((address_space(1))) void*)g,
        (__attribute__((address_space(3))) void*)s, 16, 0, 0);
}

// -------- feat: L2-normalize + bf16 copy + diag + label histogram --------
__global__ void norm_feat(const float* __restrict__ src, float* __restrict__ dst,
                          float* __restrict__ sq, __bf16* __restrict__ dstb,
                          float* __restrict__ diag, const int* __restrict__ labels,
                          int* __restrict__ counts) {
    int row = blockIdx.x * 4 + (threadIdx.x >> 6);
    int lane = threadIdx.x & 63;
    float f0 = src[row * DN + lane];
    float f1 = src[row * DN + 64 + lane];
    float ss = f0 * f0 + f1 * f1;
    #pragma unroll
    for (int o = 32; o > 0; o >>= 1) ss += __shfl_xor(ss, o);
    float inv = 1.0f / fmaxf(sqrtf(ss), 1e-12f);
    float n0 = f0 * inv, n1 = f1 * inv;
    dst[row * DN + lane] = n0;
    dst[row * DN + 64 + lane] = n1;
    __bf16 b0 = (__bf16)n0, b1 = (__bf16)n1;
    dstb[row * DN + lane] = b0;
    dstb[row * DN + 64 + lane] = b1;
    float fb0 = (float)b0, fb1 = (float)b1;
    float sb = fb0 * fb0 + fb1 * fb1;
    #pragma unroll
    for (int o = 32; o > 0; o >>= 1) sb += __shfl_xor(sb, o);
    if (lane == 0) {
        diag[row] = sb;
        sq[row] = ss * inv * inv;
        atomicAdd(&counts[labels[row]], 1);
    }
}

// -------- means: normalize (fp32) + yy + raw-bf16 copy padded to 1024 rows --------
__global__ void norm_means(const float* __restrict__ src, float* __restrict__ dst,
                           float* __restrict__ sq, __bf16* __restrict__ dstb) {
    int row = blockIdx.x * 4 + (threadIdx.x >> 6);   // 0..1023
    int lane = threadIdx.x & 63;
    float f0 = (row < CN) ? src[row * DN + lane] : 0.f;
    float f1 = (row < CN) ? src[row * DN + 64 + lane] : 0.f;
    dstb[row * DN + lane] = (__bf16)f0;
    dstb[row * DN + 64 + lane] = (__bf16)f1;
    if (row >= CN) return;
    float ss = f0 * f0 + f1 * f1;
    #pragma unroll
    for (int o = 32; o > 0; o >>= 1) ss += __shfl_xor(ss, o);
    float inv = 1.0f / fmaxf(sqrtf(ss), 1e-12f);
    dst[row * DN + lane] = f0 * inv;
    dst[row * DN + 64 + lane] = f1 * inv;
    if (lane == 0) sq[row] = ss;
}

// -------- mega kernel: 64-row blocks, single 32KB LDS B-tile, 3 blocks/CU --------
// [0,576) scl-tri | [576,1600) nsd | [1600,2112) csum
__global__ __launch_bounds__(256, 3) void mega_kernel(
        const __bf16* __restrict__ featb, const __bf16* __restrict__ meansb,
        const float* __restrict__ featn, const int* __restrict__ labels,
        const float* __restrict__ xx, const float* __restrict__ yy,
        float* __restrict__ out, float* __restrict__ pl,
        float* __restrict__ bottom, float* __restrict__ csum) {
    __shared__ uint4 sh[2048];          // one 128x128 bf16 tile, XOR-swizzled
    int bx = blockIdx.x;
    int tid = threadIdx.x;
    int lane = tid & 63, w = tid >> 6;
    int q = lane >> 4, l15 = lane & 15;
    int wrow = (w >> 1) * 32, wcol = (w & 1) * 64;

    // async-stage one 128x128 tile (swizzle folded into per-lane source chunk)
    auto stageA = [&](const uint4* src, int row0) {
        #pragma unroll
        for (int s = 0; s < 8; s++) {
            int rb = w * 32 + s * 4;
            int r = rb + q;
            async16(&src[(size_t)(row0 + r) * 16 + (l15 ^ (r & 7))], &sh[rb * 16]);
        }
    };

    if (bx < NB_SCL) {
        // ---- SCL: 64-row block a (A = a>>1), strip of <=8 128-col j-tiles J>=A ----
        int rem = bx, a = 0;
        while (true) { int ns = (64 - (a >> 1) + 7) >> 3; if (rem < ns) break; rem -= ns; ++a; }
        int A = a >> 1;
        int J0 = A + rem * 8;
        int len = min(8, 64 - J0);
        int i0 = a * 64;
        const uint4* fv = (const uint4*)featb;

        bf16x8 af[2][4];
        #pragma unroll
        for (int ii = 0; ii < 2; ii++) {
            size_t r = (size_t)(i0 + wrow + ii * 16 + l15) * 16;
            #pragma unroll
            for (int kk = 0; kk < 4; kk++)
                af[ii][kk] = *(const bf16x8*)&fv[r + kk * 4 + q];
        }
        float bs[2][4] = {};

        for (int t = 0; t < len; t++) {
            int J = J0 + t;
            int j0 = J * 128;
            __syncthreads();            // previous tile's LDS readers done
            stageA(fv, j0);
            __syncthreads();            // emits vmcnt(0) drain + barrier

            f32x4 acc[2][4];
            #pragma unroll
            for (int ii = 0; ii < 2; ii++)
                #pragma unroll
                for (int jj = 0; jj < 4; jj++) acc[ii][jj] = (f32x4){0.f, 0.f, 0.f, 0.f};
            #pragma unroll
            for (int kk = 0; kk < 4; kk++) {
                bf16x8 bfv[4];
                #pragma unroll
                for (int jj = 0; jj < 4; jj++) {
                    int r = wcol + jj * 16 + l15;
                    bfv[jj] = *(const bf16x8*)&sh[r * 16 + ((kk * 4 + q) ^ (r & 7))];
                }
                #pragma unroll
                for (int ii = 0; ii < 2; ii++)
                    #pragma unroll
                    for (int jj = 0; jj < 4; jj++)
                        acc[ii][jj] = __builtin_amdgcn_mfma_f32_16x16x32_bf16(
                            af[ii][kk], bfv[jj], acc[ii][jj], 0, 0, 0);
            }

            float cp[4] = {0.f, 0.f, 0.f, 0.f};
            #pragma unroll
            for (int ii = 0; ii < 2; ii++)
                #pragma unroll
                for (int jj = 0; jj < 4; jj++)
                    #pragma unroll
                    for (int r4 = 0; r4 < 4; r4++) {
                        float e = exp2f(acc[ii][jj][r4] * EXP2C);
                        bs[ii][r4] += e;
                        cp[jj] += e;
                    }
            if (J != A) {      // mirror column sums -> bottom[j] (skip diagonal 128-pair)
                #pragma unroll
                for (int jj = 0; jj < 4; jj++) {
                    float c = cp[jj];
                    c += __shfl_xor(c, 16);
                    c += __shfl_xor(c, 32);
                    if (lane < 16)
                        atomicAdd(&bottom[j0 + wcol + jj * 16 + l15], c);
                }
            }
        }
        int ibase = i0 + wrow + q * 4;
        #pragma unroll
        for (int ii = 0; ii < 2; ii++)
            #pragma unroll
            for (int r4 = 0; r4 < 4; r4++) {
                float b = bs[ii][r4];
                #pragma unroll
                for (int o = 8; o > 0; o >>= 1) b += __shfl_xor(b, o);
                if (l15 == 0) atomicAdd(&bottom[ibase + ii * 16 + r4], b);
            }

    } else if (bx < NB_SCL + NB_NSD) {
        // ---- NSD: 64 rows x 128 cols, B tile in LDS, A-frags from global.
        //      Bounded logits -> direct exp-sum ----
        int b = bx - NB_SCL;
        int i0 = (b >> 3) * 64, j0 = (b & 7) * 128;
        const uint4* fv = (const uint4*)featb;
        stageA((const uint4*)meansb, j0);

        bf16x8 af[2][4];
        #pragma unroll
        for (int ii = 0; ii < 2; ii++) {
            size_t r = (size_t)(i0 + wrow + ii * 16 + l15) * 16;
            #pragma unroll
            for (int kk = 0; kk < 4; kk++)
                af[ii][kk] = *(const bf16x8*)&fv[r + kk * 4 + q];
        }
        __syncthreads();                // drain DMAs + barrier

        f32x4 acc[2][4];
        #pragma unroll
        for (int ii = 0; ii < 2; ii++)
            #pragma unroll
            for (int jj = 0; jj < 4; jj++) acc[ii][jj] = (f32x4){0.f, 0.f, 0.f, 0.f};
        #pragma unroll
        for (int kk = 0; kk < 4; kk++) {
            bf16x8 bfv[4];
            #pragma unroll
            for (int jj = 0; jj < 4; jj++) {
                int r = wcol + jj * 16 + l15;
                bfv[jj] = *(const bf16x8*)&sh[r * 16 + ((kk * 4 + q) ^ (r & 7))];
            }
            #pragma unroll
            for (int ii = 0; ii < 2; ii++)
                #pragma unroll
                for (int jj = 0; jj < 4; jj++)
                    acc[ii][jj] = __builtin_amdgcn_mfma_f32_16x16x32_bf16(
                        af[ii][kk], bfv[jj], acc[ii][jj], 0, 0, 0);
        }
        int jg[4]; float yv[4];
        #pragma unroll
        for (int jj = 0; jj < 4; jj++) {
            jg[jj] = j0 + wcol + jj * 16 + l15;
            yv[jj] = (jg[jj] < CN) ? yy[jg[jj]] : 0.f;
        }
        int pslot = ((b & 7) * 2 + (w & 1)) * BN;
        int ibase = i0 + wrow + q * 4;
        #pragma unroll
        for (int ii = 0; ii < 2; ii++) {
            int rbase = ibase + ii * 16;
            float4 xv = ((const float4*)xx)[rbase >> 2];
            int4 lv = ((const int4*)labels)[rbase >> 2];
            float xa[4] = {xv.x, xv.y, xv.z, xv.w};
            int la[4] = {lv.x, lv.y, lv.z, lv.w};
            #pragma unroll
            for (int r4 = 0; r4 < 4; r4++) {
                int ig = rbase + r4;
                float s = 0.f;
                #pragma unroll
                for (int jj = 0; jj < 4; jj++) {
                    float v = -0.5f * (xa[r4] - 2.f * acc[ii][jj][r4] + yv[jj]);
                    bool ok = (jg[jj] < CN);
                    if (ok) out[(size_t)ig * CN + jg[jj]] = v;
                    float l = (jg[jj] == la[r4]) ? 1.5f * v : v;
                    s += ok ? __expf(l) : 0.f;
                }
                #pragma unroll
                for (int o = 8; o > 0; o >>= 1) s += __shfl_xor(s, o);
                if (l15 == 0) pl[pslot + ig] = s;
            }
        }

    } else {
        // ---- csum: class-sum vectors via atomics ----
        int b2 = bx - NB_SCL - NB_NSD;
        for (int idx = b2 * 256 + tid; idx < BN * DN; idx += NB_CSUM * 256) {
            int row = idx >> 7, d = idx & 127;
            atomicAdd(&csum[labels[row] * DN + d], featn[idx]);
        }
    }
}

// -------- fused per-row epilogue + full loss reduction (512 blocks x 16 rows) --------
__global__ void cemp_kernel(const float* __restrict__ featn, const float* __restrict__ meansn,
        const float* __restrict__ csum, const int* __restrict__ labels,
        const float* __restrict__ pl, const float* __restrict__ out,
        const float* __restrict__ bottom, const int* __restrict__ counts,
        const float* __restrict__ diag, const float* __restrict__ xx,
        float* __restrict__ red) {
    int tid = threadIdx.x;
    int lane = tid & 63, w = tid >> 6;
    float a_sp = 0.f, a_nv = 0.f, a_ce = 0.f, a_mg = 0.f;
    for (int pass = 0; pass < 4; pass++) {
        int row = blockIdx.x * 16 + pass * 4 + w;
        int lab = labels[row];
        float f0 = featn[row * DN + lane],  f1 = featn[row * DN + 64 + lane];
        float m0 = meansn[lab * DN + lane], m1 = meansn[lab * DN + 64 + lane];
        float c0 = csum[lab * DN + lane],   c1 = csum[lab * DN + 64 + lane];
        float d0 = f0 - m0, d1 = f1 - m1;
        float ss = d0 * d0 + d1 * d1;
        float pp = f0 * c0 + f1 * c1;
        #pragma unroll
        for (int o = 32; o > 0; o >>= 1) {
            ss += __shfl_xor(ss, o);
            pp += __shfl_xor(pp, o);
        }
        if (lane == 0) {
            float S = 0.f;
            #pragma unroll
            for (int k = 0; k < 16; k++) S += pl[k * BN + row];
            a_ce += logf(S) - 1.5f * out[(size_t)row * CN + lab];
            a_mg += ss;
            float bot = bottom[row] - __expf(diag[row] * INVT);  // exclude j==i
            float pv = (pp - xx[row]) * INVT;                    // exclude j==i
            int c = counts[lab] - 1;
            if (c > 0) {
                a_sp += pv / (float)c - logf(bot);
                a_nv += 1.f;
            }
        }
    }
    __shared__ float r4[4][4];
    if (lane == 0) { r4[w][0] = a_sp; r4[w][1] = a_nv; r4[w][2] = a_ce; r4[w][3] = a_mg; }
    __syncthreads();
    if (tid < 4)
        atomicAdd(&red[tid], r4[0][tid] + r4[1][tid] + r4[2][tid] + r4[3][tid]);
}

__global__ void final_fin(const float* __restrict__ red, float* __restrict__ loss_out) {
    float SP = red[0], NV = red[1], CE = red[2], MG = red[3];
    float scl = -SP / fmaxf(NV, 1.f);
    loss_out[0] = 0.9f * (CE / (float)BN) + 0.1f * scl + 0.5f * (MG / (2.f * (float)BN));
}

extern "C" void kernel_launch(void* const* d_in, const int* in_sizes, int n_in,
                              void* d_out, int out_size, void* d_ws, size_t ws_size,
                              hipStream_t stream) {
    const float* feat   = (const float*)d_in[0];
    const int*   labels = (const int*)d_in[1];
    const float* means  = (const float*)d_in[2];
    float* out = (float*)d_out;
    float* ws  = (float*)d_ws;

    float*  featn  = ws + F_FEATN;
    float*  meansn = ws + F_MEANSN;
    float*  xx     = ws + F_XX;
    float*  yy     = ws + F_YY;
    float*  diag   = ws + F_DIAG;
    __bf16* featb  = (__bf16*)(ws + F_FEATB);
    __bf16* meansb = (__bf16*)(ws + F_MEANSB);
    float*  pl     = ws + F_PL;
    float*  bottom = ws + F_BOT;
    int*    counts = (int*)(ws + F_CNT);
    float*  csum   = ws + F_CSUM;
    float*  red    = ws + F_RED;

    // zero bottom + counts + csum + red (contiguous)
    hipMemsetAsync(ws + F_BOT, 0, (size_t)(8192 + 1000 + 128000 + 4) * sizeof(float), stream);

    norm_feat<<<2048, 256, 0, stream>>>(feat, featn, xx, featb, diag, labels, counts);
    norm_means<<<256, 256, 0, stream>>>(means, meansn, yy, meansb);
    mega_kernel<<<NB_SCL + NB_NSD + NB_CSUM, 256, 0, stream>>>(
        featb, meansb, featn, labels, xx, yy, out, pl, bottom, csum);
    cemp_kernel<<<512, 256, 0, stream>>>(featn, meansn, csum, labels, pl, out,
                                         bottom, counts, diag, xx, red);
    final_fin<<<1, 1, 0, stream>>>(red, out + (size_t)BN * CN);
}

// Round 13
// 123.226 us; speedup vs baseline: 1.4136x; 1.0190x over previous
//
#include <hip/hip_runtime.h>
#include <math.h>

#define BN 8192
#define CN 1000
#define DN 128
#define INVT (1.0f/0.3f)
#define EXP2C 4.80898346962988f   // (1/0.3) * log2(e)

typedef __bf16 bf16x8 __attribute__((ext_vector_type(8)));
typedef float  f32x4  __attribute__((ext_vector_type(4)));

// ws layout in floats
#define F_FEATN  0          // 8192*128
#define F_MEANSN 1048576    // 1000*128
#define F_XX     1176576    // 8192
#define F_YY     1184768    // 1000
#define F_DIAG   1185768    // 8192
#define F_FEATB  1193960    // 8192*128 bf16
#define F_MEANSB 1718248    // 1024*128 bf16 (raw, zero-padded)
#define F_PL     1808360    // 16*8192 CE partial sums
#define F_BOT    1939432    // 8192   -- zeroed region start
#define F_CNT    1947624    // 1000 ints
#define F_CSUM   1948624    // 1000*128
#define F_RED    2076624    // 4 loss accumulators (sp, nv, ce, mg)
#define NZERO    (8192 + 1000 + 128000 + 4)   // floats to zero from F_BOT

// norm_all block ranges
#define NB_FEAT  2048
#define NB_MEANS 256
#define NB_ZERO  64

// mega-kernel block ranges: 64-row blocks, single 32KB LDS buffer, (256,3)
#define NB_SCL  576   // (a, strip): a=64-row block (128 of them), strips of <=8 j-tiles, J>=A=a/2
#define NB_NSD  1024  // 128 i-blocks(64 rows) x 8 j-tiles(128 cols)
#define NB_CSUM 512

__device__ __forceinline__ void async16(const void* g, void* s) {
    __builtin_amdgcn_global_load_lds(
        (const __attribute__((address_space(1))) void*)g,
        (__attribute__((address_space(3))) void*)s, 16, 0, 0);
}

// -------- fused prep: feat-normalize | means-normalize | zero accumulators --------
__global__ void norm_all(const float* __restrict__ feat, const float* __restrict__ means,
                         float* __restrict__ featn, float* __restrict__ meansn,
                         float* __restrict__ xx, float* __restrict__ yy,
                         __bf16* __restrict__ featb, __bf16* __restrict__ meansb,
                         float* __restrict__ diag, const int* __restrict__ labels,
                         int* __restrict__ counts, float* __restrict__ zbase) {
    int bx = blockIdx.x;
    int lane = threadIdx.x & 63;
    if (bx < NB_FEAT) {
        int row = bx * 4 + (threadIdx.x >> 6);
        float f0 = feat[row * DN + lane];
        float f1 = feat[row * DN + 64 + lane];
        float ss = f0 * f0 + f1 * f1;
        #pragma unroll
        for (int o = 32; o > 0; o >>= 1) ss += __shfl_xor(ss, o);
        float inv = 1.0f / fmaxf(sqrtf(ss), 1e-12f);
        float n0 = f0 * inv, n1 = f1 * inv;
        featn[row * DN + lane] = n0;
        featn[row * DN + 64 + lane] = n1;
        __bf16 b0 = (__bf16)n0, b1 = (__bf16)n1;
        featb[row * DN + lane] = b0;
        featb[row * DN + 64 + lane] = b1;
        float fb0 = (float)b0, fb1 = (float)b1;
        float sb = fb0 * fb0 + fb1 * fb1;
        #pragma unroll
        for (int o = 32; o > 0; o >>= 1) sb += __shfl_xor(sb, o);
        if (lane == 0) {
            diag[row] = sb;
            xx[row] = ss * inv * inv;
            atomicAdd(&counts[labels[row]], 1);   // counts zeroed by zero-range below?  NO:
            // counts are in the zeroed region written by other blocks of THIS kernel --
            // ordering between blocks is undefined, so counts must NOT be zeroed here.
            // (They are zeroed by the zero-range of the PREVIOUS kernel? None exists.)
            // -> handled: hist moved to cemp-safe scheme below (see note) -- actually
            //    counts zeroing stays in this kernel is a RACE. Fixed by keeping the
            //    tiny memset before this kernel for counts+bottom+csum+red instead.
        }
    } else if (bx < NB_FEAT + NB_MEANS) {
        int row = (bx - NB_FEAT) * 4 + (threadIdx.x >> 6);   // 0..1023
        float f0 = (row < CN) ? means[row * DN + lane] : 0.f;
        float f1 = (row < CN) ? means[row * DN + 64 + lane] : 0.f;
        meansb[row * DN + lane] = (__bf16)f0;
        meansb[row * DN + 64 + lane] = (__bf16)f1;
        if (row >= CN) return;
        float ss = f0 * f0 + f1 * f1;
        #pragma unroll
        for (int o = 32; o > 0; o >>= 1) ss += __shfl_xor(ss, o);
        float inv = 1.0f / fmaxf(sqrtf(ss), 1e-12f);
        meansn[row * DN + lane] = f0 * inv;
        meansn[row * DN + 64 + lane] = f1 * inv;
        if (lane == 0) yy[row] = ss;
    } else {
        // zero bottom + csum + red (NOT counts -- counts are atomically
        // incremented by feat blocks of this same kernel; they are zeroed by
        // the hipMemsetAsync that still precedes this kernel)
        int b2 = bx - NB_FEAT - NB_MEANS;
        for (int idx = b2 * 256 + (int)threadIdx.x; idx < NZERO; idx += NB_ZERO * 256) {
            float* p = zbase + idx;
            // skip the counts subrange [8192, 9192) -- memset owns it
            if (idx < 8192 || idx >= 9192) *p = 0.f;
        }
    }
}

// -------- mega kernel: 64-row blocks, single 32KB LDS B-tile, 3 blocks/CU --------
// [0,576) scl-tri | [576,1600) nsd | [1600,2112) csum
__global__ __launch_bounds__(256, 3) void mega_kernel(
        const __bf16* __restrict__ featb, const __bf16* __restrict__ meansb,
        const float* __restrict__ featn, const int* __restrict__ labels,
        const float* __restrict__ xx, const float* __restrict__ yy,
        float* __restrict__ out, float* __restrict__ pl,
        float* __restrict__ bottom, float* __restrict__ csum) {
    __shared__ uint4 sh[2048];          // one 128x128 bf16 tile, XOR-swizzled
    int bx = blockIdx.x;
    int tid = threadIdx.x;
    int lane = tid & 63, w = tid >> 6;
    int q = lane >> 4, l15 = lane & 15;
    int wrow = (w >> 1) * 32, wcol = (w & 1) * 64;

    auto stageA = [&](const uint4* src, int row0) {
        #pragma unroll
        for (int s = 0; s < 8; s++) {
            int rb = w * 32 + s * 4;
            int r = rb + q;
            async16(&src[(size_t)(row0 + r) * 16 + (l15 ^ (r & 7))], &sh[rb * 16]);
        }
    };

    if (bx < NB_SCL) {
        // ---- SCL: 64-row block a (A = a>>1), strip of <=8 128-col j-tiles J>=A ----
        int rem = bx, a = 0;
        while (true) { int ns = (64 - (a >> 1) + 7) >> 3; if (rem < ns) break; rem -= ns; ++a; }
        int A = a >> 1;
        int J0 = A + rem * 8;
        int len = min(8, 64 - J0);
        int i0 = a * 64;
        const uint4* fv = (const uint4*)featb;

        bf16x8 af[2][4];
        #pragma unroll
        for (int ii = 0; ii < 2; ii++) {
            size_t r = (size_t)(i0 + wrow + ii * 16 + l15) * 16;
            #pragma unroll
            for (int kk = 0; kk < 4; kk++)
                af[ii][kk] = *(const bf16x8*)&fv[r + kk * 4 + q];
        }
        float bs[2][4] = {};

        for (int t = 0; t < len; t++) {
            int J = J0 + t;
            int j0 = J * 128;
            __syncthreads();
            stageA(fv, j0);
            __syncthreads();

            f32x4 acc[2][4];
            #pragma unroll
            for (int ii = 0; ii < 2; ii++)
                #pragma unroll
                for (int jj = 0; jj < 4; jj++) acc[ii][jj] = (f32x4){0.f, 0.f, 0.f, 0.f};
            #pragma unroll
            for (int kk = 0; kk < 4; kk++) {
                bf16x8 bfv[4];
                #pragma unroll
                for (int jj = 0; jj < 4; jj++) {
                    int r = wcol + jj * 16 + l15;
                    bfv[jj] = *(const bf16x8*)&sh[r * 16 + ((kk * 4 + q) ^ (r & 7))];
                }
                #pragma unroll
                for (int ii = 0; ii < 2; ii++)
                    #pragma unroll
                    for (int jj = 0; jj < 4; jj++)
                        acc[ii][jj] = __builtin_amdgcn_mfma_f32_16x16x32_bf16(
                            af[ii][kk], bfv[jj], acc[ii][jj], 0, 0, 0);
            }

            float cp[4] = {0.f, 0.f, 0.f, 0.f};
            #pragma unroll
            for (int ii = 0; ii < 2; ii++)
                #pragma unroll
                for (int jj = 0; jj < 4; jj++)
                    #pragma unroll
                    for (int r4 = 0; r4 < 4; r4++) {
                        float e = exp2f(acc[ii][jj][r4] * EXP2C);
                        bs[ii][r4] += e;
                        cp[jj] += e;
                    }
            if (J != A) {
                #pragma unroll
                for (int jj = 0; jj < 4; jj++) {
                    float c = cp[jj];
                    c += __shfl_xor(c, 16);
                    c += __shfl_xor(c, 32);
                    if (lane < 16)
                        atomicAdd(&bottom[j0 + wcol + jj * 16 + l15], c);
                }
            }
        }
        int ibase = i0 + wrow + q * 4;
        #pragma unroll
        for (int ii = 0; ii < 2; ii++)
            #pragma unroll
            for (int r4 = 0; r4 < 4; r4++) {
                float b = bs[ii][r4];
                #pragma unroll
                for (int o = 8; o > 0; o >>= 1) b += __shfl_xor(b, o);
                if (l15 == 0) atomicAdd(&bottom[ibase + ii * 16 + r4], b);
            }

    } else if (bx < NB_SCL + NB_NSD) {
        // ---- NSD: 64 rows x 128 cols, bounded logits -> direct exp-sum ----
        int b = bx - NB_SCL;
        int i0 = (b >> 3) * 64, j0 = (b & 7) * 128;
        const uint4* fv = (const uint4*)featb;
        stageA((const uint4*)meansb, j0);

        bf16x8 af[2][4];
        #pragma unroll
        for (int ii = 0; ii < 2; ii++) {
            size_t r = (size_t)(i0 + wrow + ii * 16 + l15) * 16;
            #pragma unroll
            for (int kk = 0; kk < 4; kk++)
                af[ii][kk] = *(const bf16x8*)&fv[r + kk * 4 + q];
        }
        __syncthreads();

        f32x4 acc[2][4];
        #pragma unroll
        for (int ii = 0; ii < 2; ii++)
            #pragma unroll
            for (int jj = 0; jj < 4; jj++) acc[ii][jj] = (f32x4){0.f, 0.f, 0.f, 0.f};
        #pragma unroll
        for (int kk = 0; kk < 4; kk++) {
            bf16x8 bfv[4];
            #pragma unroll
            for (int jj = 0; jj < 4; jj++) {
                int r = wcol + jj * 16 + l15;
                bfv[jj] = *(const bf16x8*)&sh[r * 16 + ((kk * 4 + q) ^ (r & 7))];
            }
            #pragma unroll
            for (int ii = 0; ii < 2; ii++)
                #pragma unroll
                for (int jj = 0; jj < 4; jj++)
                    acc[ii][jj] = __builtin_amdgcn_mfma_f32_16x16x32_bf16(
                        af[ii][kk], bfv[jj], acc[ii][jj], 0, 0, 0);
        }
        int jg[4]; float yv[4];
        #pragma unroll
        for (int jj = 0; jj < 4; jj++) {
            jg[jj] = j0 + wcol + jj * 16 + l15;
            yv[jj] = (jg[jj] < CN) ? yy[jg[jj]] : 0.f;
        }
        int pslot = ((b & 7) * 2 + (w & 1)) * BN;
        int ibase = i0 + wrow + q * 4;
        #pragma unroll
        for (int ii = 0; ii < 2; ii++) {
            int rbase = ibase + ii * 16;
            float4 xv = ((const float4*)xx)[rbase >> 2];
            int4 lv = ((const int4*)labels)[rbase >> 2];
            float xa[4] = {xv.x, xv.y, xv.z, xv.w};
            int la[4] = {lv.x, lv.y, lv.z, lv.w};
            #pragma unroll
            for (int r4 = 0; r4 < 4; r4++) {
                int ig = rbase + r4;
                float s = 0.f;
                #pragma unroll
                for (int jj = 0; jj < 4; jj++) {
                    float v = -0.5f * (xa[r4] - 2.f * acc[ii][jj][r4] + yv[jj]);
                    bool ok = (jg[jj] < CN);
                    if (ok) out[(size_t)ig * CN + jg[jj]] = v;
                    float l = (jg[jj] == la[r4]) ? 1.5f * v : v;
                    s += ok ? __expf(l) : 0.f;
                }
                #pragma unroll
                for (int o = 8; o > 0; o >>= 1) s += __shfl_xor(s, o);
                if (l15 == 0) pl[pslot + ig] = s;
            }
        }

    } else {
        // ---- csum: class-sum vectors via atomics ----
        int b2 = bx - NB_SCL - NB_NSD;
        for (int idx = b2 * 256 + tid; idx < BN * DN; idx += NB_CSUM * 256) {
            int row = idx >> 7, d = idx & 127;
            atomicAdd(&csum[labels[row] * DN + d], featn[idx]);
        }
    }
}

// -------- fused per-row epilogue + full loss reduction (512 blocks x 16 rows) --------
__global__ void cemp_kernel(const float* __restrict__ featn, const float* __restrict__ meansn,
        const float* __restrict__ csum, const int* __restrict__ labels,
        const float* __restrict__ pl, const float* __restrict__ out,
        const float* __restrict__ bottom, const int* __restrict__ counts,
        const float* __restrict__ diag, const float* __restrict__ xx,
        float* __restrict__ red) {
    int tid = threadIdx.x;
    int lane = tid & 63, w = tid >> 6;
    float a_sp = 0.f, a_nv = 0.f, a_ce = 0.f, a_mg = 0.f;
    for (int pass = 0; pass < 4; pass++) {
        int row = blockIdx.x * 16 + pass * 4 + w;
        int lab = labels[row];
        float f0 = featn[row * DN + lane],  f1 = featn[row * DN + 64 + lane];
        float m0 = meansn[lab * DN + lane], m1 = meansn[lab * DN + 64 + lane];
        float c0 = csum[lab * DN + lane],   c1 = csum[lab * DN + 64 + lane];
        float d0 = f0 - m0, d1 = f1 - m1;
        float ss = d0 * d0 + d1 * d1;
        float pp = f0 * c0 + f1 * c1;
        #pragma unroll
        for (int o = 32; o > 0; o >>= 1) {
            ss += __shfl_xor(ss, o);
            pp += __shfl_xor(pp, o);
        }
        if (lane == 0) {
            float S = 0.f;
            #pragma unroll
            for (int k = 0; k < 16; k++) S += pl[k * BN + row];
            a_ce += __logf(S) - 1.5f * out[(size_t)row * CN + lab];
            a_mg += ss;
            float bot = bottom[row] - __expf(diag[row] * INVT);  // exclude j==i
            float pv = (pp - xx[row]) * INVT;                    // exclude j==i
            int c = counts[lab] - 1;
            if (c > 0) {
                a_sp += pv / (float)c - __logf(bot);
                a_nv += 1.f;
            }
        }
    }
    __shared__ float r4[4][4];
    if (lane == 0) { r4[w][0] = a_sp; r4[w][1] = a_nv; r4[w][2] = a_ce; r4[w][3] = a_mg; }
    __syncthreads();
    if (tid < 4)
        atomicAdd(&red[tid], r4[0][tid] + r4[1][tid] + r4[2][tid] + r4[3][tid]);
}

__global__ void final_fin(const float* __restrict__ red, float* __restrict__ loss_out) {
    float SP = red[0], NV = red[1], CE = red[2], MG = red[3];
    float scl = -SP / fmaxf(NV, 1.f);
    loss_out[0] = 0.9f * (CE / (float)BN) + 0.1f * scl + 0.5f * (MG / (2.f * (float)BN));
}

extern "C" void kernel_launch(void* const* d_in, const int* in_sizes, int n_in,
                              void* d_out, int out_size, void* d_ws, size_t ws_size,
                              hipStream_t stream) {
    const float* feat   = (const float*)d_in[0];
    const int*   labels = (const int*)d_in[1];
    const float* means  = (const float*)d_in[2];
    float* out = (float*)d_out;
    float* ws  = (float*)d_ws;

    float*  featn  = ws + F_FEATN;
    float*  meansn = ws + F_MEANSN;
    float*  xx     = ws + F_XX;
    float*  yy     = ws + F_YY;
    float*  diag   = ws + F_DIAG;
    __bf16* featb  = (__bf16*)(ws + F_FEATB);
    __bf16* meansb = (__bf16*)(ws + F_MEANSB);
    float*  pl     = ws + F_PL;
    float*  bottom = ws + F_BOT;
    int*    counts = (int*)(ws + F_CNT);
    float*  csum   = ws + F_CSUM;
    float*  red    = ws + F_RED;

    // counts must be zero BEFORE norm_all's histogram atomics (inter-block order
    // within norm_all is undefined) -- tiny 4 KB memset; bottom/csum/red are zeroed
    // by norm_all's zero-range (they're only read by mega, which launches after).
    hipMemsetAsync(counts, 0, 1000 * sizeof(int), stream);

    norm_all<<<NB_FEAT + NB_MEANS + NB_ZERO, 256, 0, stream>>>(
        feat, means, featn, meansn, xx, yy, featb, meansb, diag, labels, counts,
        ws + F_BOT);
    mega_kernel<<<NB_SCL + NB_NSD + NB_CSUM, 256, 0, stream>>>(
        featb, meansb, featn, labels, xx, yy, out, pl, bottom, csum);
    cemp_kernel<<<512, 256, 0, stream>>>(featn, meansn, csum, labels, pl, out,
                                         bottom, counts, diag, xx, red);
    final_fin<<<1, 1, 0, stream>>>(red, out + (size_t)BN * CN);
}